// Round 1
// baseline (1062.301 us; speedup 1.0000x reference)
//
#include <hip/hip_runtime.h>
#include <hip/hip_bf16.h>
#include <cstdint>

#define NEG_SLOPE 0.2f

// ---------------------------------------------------------------------------
// Generic fp32 tiled GEMM: C[M,N] = A[M,K] @ B[K,N]. 64x64 tile, 256 thr, 4x4.
// K divisible by 32, N divisible by 64 (true for 128/512/64 and 512/64).
// ---------------------------------------------------------------------------
__global__ __launch_bounds__(256) void gemm_tiled(
    const float* __restrict__ A, const float* __restrict__ B,
    float* __restrict__ C, int M, int N, int K) {
  __shared__ float As[32][65];
  __shared__ float Bs[32][65];
  const int tid = threadIdx.x;
  const int tx = tid & 15, ty = tid >> 4;
  const int row0 = blockIdx.y * 64;
  const int col0 = blockIdx.x * 64;
  float acc[4][4] = {};
  for (int k0 = 0; k0 < K; k0 += 32) {
    for (int i = tid; i < 64 * 32; i += 256) {
      int r = i >> 5, c = i & 31;
      int gr = row0 + r;
      As[c][r] = (gr < M) ? A[(size_t)gr * K + k0 + c] : 0.f;
    }
    for (int i = tid; i < 32 * 64; i += 256) {
      int r = i >> 6, c = i & 63;
      Bs[r][c] = B[(size_t)(k0 + r) * N + col0 + c];
    }
    __syncthreads();
#pragma unroll
    for (int kk = 0; kk < 32; ++kk) {
      float a[4], b[4];
#pragma unroll
      for (int i = 0; i < 4; ++i) a[i] = As[kk][ty * 4 + i];
#pragma unroll
      for (int j = 0; j < 4; ++j) b[j] = Bs[kk][tx * 4 + j];
#pragma unroll
      for (int i = 0; i < 4; ++i)
#pragma unroll
        for (int j = 0; j < 4; ++j) acc[i][j] = fmaf(a[i], b[j], acc[i][j]);
    }
    __syncthreads();
  }
  for (int i = 0; i < 4; ++i) {
    int r = row0 + ty * 4 + i;
    if (r < M) {
#pragma unroll
      for (int j = 0; j < 4; ++j)
        C[(size_t)r * N + col0 + tx * 4 + j] = acc[i][j];
    }
  }
}

// ---------------------------------------------------------------------------
// al_s[n*H+h] = sum_c h[n,h,c]*a_src[h,c];  al_d likewise. One wave per (n,h).
// ---------------------------------------------------------------------------
__global__ __launch_bounds__(256) void compute_al(
    const float* __restrict__ h, const float* __restrict__ a_src,
    const float* __restrict__ a_dst, float* __restrict__ al_s,
    float* __restrict__ al_d, int nwaves, int H) {
  int w = (blockIdx.x * 256 + threadIdx.x) >> 6;
  int lane = threadIdx.x & 63;
  if (w >= nwaves) return;
  int hh = w % H;
  float v = h[(size_t)w * 64 + lane];
  float vs = v * a_src[hh * 64 + lane];
  float vd = v * a_dst[hh * 64 + lane];
#pragma unroll
  for (int off = 32; off; off >>= 1) {
    vs += __shfl_xor(vs, off);
    vd += __shfl_xor(vd, off);
  }
  if (lane == 0) {
    al_s[w] = vs;
    al_d[w] = vd;
  }
}

// ---------------------------------------------------------------------------
// CSR build
// ---------------------------------------------------------------------------
__global__ void count_kernel(const int* __restrict__ dst, int* __restrict__ cnt,
                             int E) {
  int e = blockIdx.x * 256 + threadIdx.x;
  if (e < E) atomicAdd(&cnt[dst[e]], 1);
}

__global__ void scan_block(const int* __restrict__ in, int* __restrict__ out,
                           int* __restrict__ bsum, int n) {
  __shared__ int sm[256];
  int gid = blockIdx.x * 256 + threadIdx.x;
  int v = (gid < n) ? in[gid] : 0;
  sm[threadIdx.x] = v;
  __syncthreads();
  for (int off = 1; off < 256; off <<= 1) {
    int t = (threadIdx.x >= off) ? sm[threadIdx.x - off] : 0;
    __syncthreads();
    sm[threadIdx.x] += t;
    __syncthreads();
  }
  if (gid < n) out[gid] = sm[threadIdx.x];
  if (threadIdx.x == 255) bsum[blockIdx.x] = sm[255];
}

__global__ void scan_bsum(int* __restrict__ bsum, int nb) {
  __shared__ int sm[256];
  int t = threadIdx.x;
  sm[t] = (t < nb) ? bsum[t] : 0;
  __syncthreads();
  for (int off = 1; off < 256; off <<= 1) {
    int v = (t >= off) ? sm[t - off] : 0;
    __syncthreads();
    sm[t] += v;
    __syncthreads();
  }
  if (t < nb) bsum[t] = sm[t];
}

__global__ void scan_final(const int* __restrict__ inc,
                           const int* __restrict__ bscan,
                           int* __restrict__ indptr, int n) {
  int gid = blockIdx.x * 256 + threadIdx.x;
  if (gid < n) {
    int add = blockIdx.x ? bscan[blockIdx.x - 1] : 0;
    indptr[gid + 1] = inc[gid] + add;
  }
  if (gid == 0) indptr[0] = 0;
}

__global__ void scatter_kernel(const int* __restrict__ src,
                               const int* __restrict__ dst,
                               const int* __restrict__ indptr,
                               int* __restrict__ fill,
                               int* __restrict__ csr_src, int E) {
  int e = blockIdx.x * 256 + threadIdx.x;
  if (e < E) {
    int dd = dst[e];
    int pos = indptr[dd] + atomicAdd(&fill[dd], 1);
    csr_src[pos] = src[e];
  }
}

// ---------------------------------------------------------------------------
// Attention layer 1: H=8, C=64 (512 channels). One block (256 thr) per node.
// out1[d] = elu( sum_e alpha_e * h1[src_e] + b1 )
// ---------------------------------------------------------------------------
__global__ __launch_bounds__(256) void attn1_kernel(
    const int* __restrict__ indptr, const int* __restrict__ csr_src,
    const float* __restrict__ al_s, const float* __restrict__ al_d,
    const float* __restrict__ h1, const float* __restrict__ b1,
    float* __restrict__ out1) {
  const int d = blockIdx.x;
  const int tid = threadIdx.x;
  const int start = indptr[d];
  const int deg = indptr[d + 1] - start;
  const int total = deg + 1;  // + self loop

  __shared__ float s_red[256];
  __shared__ float s_ald[8], s_m[8], s_den[8];
  __shared__ float s_alpha[64][8];
  __shared__ int s_srcs[64];

  if (tid < 8) s_ald[tid] = al_d[(size_t)d * 8 + tid];
  __syncthreads();

  const int h = tid & 7;
  const int le = tid >> 3;  // 32 edge-lanes per head
  const float ald = s_ald[h];

  // pass A: per-head max
  float mx = -1e30f;
  for (int e = le; e < total; e += 32) {
    int s = (e < deg) ? csr_src[start + e] : d;
    float v = al_s[(size_t)s * 8 + h] + ald;
    v = (v > 0.f) ? v : NEG_SLOPE * v;
    mx = fmaxf(mx, v);
  }
  s_red[tid] = mx;
  __syncthreads();
  for (int off = 128; off >= 8; off >>= 1) {
    if (tid < off) s_red[tid] = fmaxf(s_red[tid], s_red[tid + off]);
    __syncthreads();
  }
  if (tid < 8) s_m[tid] = s_red[tid];
  __syncthreads();

  // pass B: per-head denom
  const float m = s_m[h];
  float sm = 0.f;
  for (int e = le; e < total; e += 32) {
    int s = (e < deg) ? csr_src[start + e] : d;
    float v = al_s[(size_t)s * 8 + h] + ald;
    v = (v > 0.f) ? v : NEG_SLOPE * v;
    sm += __expf(v - m);
  }
  __syncthreads();
  s_red[tid] = sm;
  __syncthreads();
  for (int off = 128; off >= 8; off >>= 1) {
    if (tid < off) s_red[tid] += s_red[tid + off];
    __syncthreads();
  }
  if (tid < 8) s_den[tid] = 1.f / s_red[tid];
  __syncthreads();

  // pass C: weighted accumulate. thread handles channels tid and tid+256.
  float acc0 = 0.f, acc1 = 0.f;
  const int c0 = tid, c1 = tid + 256;
  const int h0 = c0 >> 6, h1i = c1 >> 6;
  for (int e0 = 0; e0 < total; e0 += 64) {
    int ne = min(64, total - e0);
    for (int i = tid; i < ne * 8; i += 256) {
      int e = i >> 3, hh = i & 7;
      int ge = e0 + e;
      int s = (ge < deg) ? csr_src[start + ge] : d;
      if (hh == 0) s_srcs[e] = s;
      float v = al_s[(size_t)s * 8 + hh] + s_ald[hh];
      v = (v > 0.f) ? v : NEG_SLOPE * v;
      s_alpha[e][hh] = __expf(v - s_m[hh]) * s_den[hh];
    }
    __syncthreads();
    for (int e = 0; e < ne; ++e) {
      const float* hrow = h1 + (size_t)s_srcs[e] * 512;
      acc0 = fmaf(s_alpha[e][h0], hrow[c0], acc0);
      acc1 = fmaf(s_alpha[e][h1i], hrow[c1], acc1);
    }
    __syncthreads();
  }
  float v0 = acc0 + b1[c0];
  float v1 = acc1 + b1[c1];
  out1[(size_t)d * 512 + c0] = (v0 > 0.f) ? v0 : __expf(v0) - 1.f;
  out1[(size_t)d * 512 + c1] = (v1 > 0.f) ? v1 : __expf(v1) - 1.f;
}

// ---------------------------------------------------------------------------
// Attention layers 2/3: H=1, C=64. One wave per node, 4 nodes per block.
// ---------------------------------------------------------------------------
__global__ __launch_bounds__(256) void attn_h1_kernel(
    const int* __restrict__ indptr, const int* __restrict__ csr_src,
    const float* __restrict__ al_s, const float* __restrict__ al_d,
    const float* __restrict__ hin, const float* __restrict__ bias,
    float* __restrict__ outp, int Nn) {
  int w = (blockIdx.x * 256 + threadIdx.x) >> 6;
  int lane = threadIdx.x & 63;
  if (w >= Nn) return;
  const int d = w;
  const int start = indptr[d];
  const int deg = indptr[d + 1] - start;
  const int total = deg + 1;
  const float ald = al_d[d];

  float mx = -1e30f;
  for (int e = lane; e < total; e += 64) {
    int s = (e < deg) ? csr_src[start + e] : d;
    float v = al_s[s] + ald;
    v = (v > 0.f) ? v : NEG_SLOPE * v;
    mx = fmaxf(mx, v);
  }
#pragma unroll
  for (int off = 32; off; off >>= 1) mx = fmaxf(mx, __shfl_xor(mx, off));

  float sm = 0.f;
  for (int e = lane; e < total; e += 64) {
    int s = (e < deg) ? csr_src[start + e] : d;
    float v = al_s[s] + ald;
    v = (v > 0.f) ? v : NEG_SLOPE * v;
    sm += __expf(v - mx);
  }
#pragma unroll
  for (int off = 32; off; off >>= 1) sm += __shfl_xor(sm, off);
  const float inv_den = 1.f / sm;

  float acc = 0.f;
  for (int e0 = 0; e0 < total; e0 += 64) {
    int ne = min(64, total - e0);
    int e = e0 + lane;
    float alpha = 0.f;
    int s = d;
    if (e < total) {
      s = (e < deg) ? csr_src[start + e] : d;
      float v = al_s[s] + ald;
      v = (v > 0.f) ? v : NEG_SLOPE * v;
      alpha = __expf(v - mx) * inv_den;
    }
    for (int j = 0; j < ne; ++j) {
      float a = __shfl(alpha, j);
      int ss = __shfl(s, j);
      acc = fmaf(a, hin[(size_t)ss * 64 + lane], acc);
    }
  }
  float v = acc + bias[lane];
  outp[(size_t)d * 64 + lane] = (v > 0.f) ? v : __expf(v) - 1.f;
}

// ---------------------------------------------------------------------------
// Global mean pool (sum part) via atomics; counts computed in final kernel.
// ---------------------------------------------------------------------------
__global__ void pool_kernel(const float* __restrict__ out3,
                            const int* __restrict__ batch,
                            float* __restrict__ sums, int Nn) {
  int idx = blockIdx.x * 256 + threadIdx.x;
  if (idx >= Nn * 64) return;
  int n = idx >> 6, c = idx & 63;
  atomicAdd(&sums[batch[n] * 64 + c], out3[idx]);
}

__global__ __launch_bounds__(256) void final_kernel(
    const float* __restrict__ sums, const int* __restrict__ batch, int Nn,
    const float* __restrict__ fcW, const float* __restrict__ fcb,
    float* __restrict__ out) {
  __shared__ int lb[65];
  __shared__ float inv_cnt[64];
  int tid = threadIdx.x;
  if (tid <= 64) {
    int lo = 0, hi = Nn;
    while (lo < hi) {
      int mid = (lo + hi) >> 1;
      if (batch[mid] < tid) lo = mid + 1; else hi = mid;
    }
    lb[tid] = lo;
  }
  __syncthreads();
  if (tid < 64) inv_cnt[tid] = 1.f / fmaxf((float)(lb[tid + 1] - lb[tid]), 1.f);
  __syncthreads();
  for (int i = tid; i < 64 * 10; i += 256) {
    int g = i / 10, o = i % 10;
    float acc = fcb[o];
    float inv = inv_cnt[g];
    for (int c = 0; c < 64; ++c)
      acc = fmaf(sums[g * 64 + c] * inv, fcW[c * 10 + o], acc);
    out[i] = acc;
  }
}

// ---------------------------------------------------------------------------
extern "C" void kernel_launch(void* const* d_in, const int* in_sizes, int n_in,
                              void* d_out, int out_size, void* d_ws,
                              size_t ws_size, hipStream_t stream) {
  const float* x = (const float*)d_in[0];
  const int* ei = (const int*)d_in[1];
  const int* batch = (const int*)d_in[2];
  const float* W1 = (const float*)d_in[3];
  const float* a1s = (const float*)d_in[4];
  const float* a1d = (const float*)d_in[5];
  const float* b1 = (const float*)d_in[6];
  const float* W2 = (const float*)d_in[7];
  const float* a2s = (const float*)d_in[8];
  const float* a2d = (const float*)d_in[9];
  const float* b2 = (const float*)d_in[10];
  const float* W3 = (const float*)d_in[11];
  const float* a3s = (const float*)d_in[12];
  const float* a3d = (const float*)d_in[13];
  const float* b3 = (const float*)d_in[14];
  const float* fcW = (const float*)d_in[15];
  const float* fcb = (const float*)d_in[16];
  float* out = (float*)d_out;

  const int N = in_sizes[0] / 128;  // 50000
  const int E = in_sizes[1] / 2;    // 800000
  const int* srcp = ei;
  const int* dstp = ei + E;

  // --- workspace layout ---
  char* ws = (char*)d_ws;
  size_t off = 0;
  auto alloc = [&](size_t bytes) -> void* {
    off = (off + 255) & ~(size_t)255;
    void* p = ws + off;
    off += bytes;
    return p;
  };
  float* h1 = (float*)alloc((size_t)N * 512 * 4);    // also reused for h2/out2/h3/out3
  float* out1 = (float*)alloc((size_t)N * 512 * 4);
  float* al_s1 = (float*)alloc((size_t)N * 8 * 4);
  float* al_d1 = (float*)alloc((size_t)N * 8 * 4);
  float* al_s2 = (float*)alloc((size_t)N * 4);
  float* al_d2 = (float*)alloc((size_t)N * 4);
  float* al_s3 = (float*)alloc((size_t)N * 4);
  float* al_d3 = (float*)alloc((size_t)N * 4);
  int* cnt = (int*)alloc((size_t)N * 4);
  int* fill = (int*)alloc((size_t)N * 4);
  int* indptr = (int*)alloc((size_t)(N + 1) * 4);
  int* csr = (int*)alloc((size_t)E * 4);
  int* incbuf = (int*)alloc((size_t)N * 4);
  int* bsum = (int*)alloc(1024 * 4);
  float* sums = (float*)alloc(64 * 64 * 4);

  // aliases into the (dead-after-attn1) h1 region
  float* h2 = h1;
  float* out2 = h1 + (size_t)N * 64;
  float* h3 = h1 + (size_t)2 * N * 64;
  float* out3 = h1 + (size_t)3 * N * 64;

  hipMemsetAsync(cnt, 0, (size_t)N * 4, stream);
  hipMemsetAsync(fill, 0, (size_t)N * 4, stream);
  hipMemsetAsync(sums, 0, 64 * 64 * 4, stream);

  const int scan_blocks = (N + 255) / 256;

  // GEMM1: h1 = x @ W1   [N,128]@[128,512]
  gemm_tiled<<<dim3(512 / 64, (N + 63) / 64), 256, 0, stream>>>(x, W1, h1, N,
                                                                512, 128);
  compute_al<<<(N * 8 + 3) / 4, 256, 0, stream>>>(h1, a1s, a1d, al_s1, al_d1,
                                                  N * 8, 8);
  // CSR build
  count_kernel<<<(E + 255) / 256, 256, 0, stream>>>(dstp, cnt, E);
  scan_block<<<scan_blocks, 256, 0, stream>>>(cnt, incbuf, bsum, N);
  scan_bsum<<<1, 256, 0, stream>>>(bsum, scan_blocks);
  scan_final<<<scan_blocks, 256, 0, stream>>>(incbuf, bsum, indptr, N);
  scatter_kernel<<<(E + 255) / 256, 256, 0, stream>>>(srcp, dstp, indptr, fill,
                                                      csr, E);
  // Layer 1 attention + bias + ELU
  attn1_kernel<<<N, 256, 0, stream>>>(indptr, csr, al_s1, al_d1, h1, b1, out1);

  // Layer 2
  gemm_tiled<<<dim3(1, (N + 63) / 64), 256, 0, stream>>>(out1, W2, h2, N, 64,
                                                         512);
  compute_al<<<(N + 3) / 4, 256, 0, stream>>>(h2, a2s, a2d, al_s2, al_d2, N, 1);
  attn_h1_kernel<<<(N + 3) / 4, 256, 0, stream>>>(indptr, csr, al_s2, al_d2, h2,
                                                  b2, out2, N);

  // Layer 3
  gemm_tiled<<<dim3(1, (N + 63) / 64), 256, 0, stream>>>(out2, W3, h3, N, 64,
                                                         64);
  compute_al<<<(N + 3) / 4, 256, 0, stream>>>(h3, a3s, a3d, al_s3, al_d3, N, 1);
  attn_h1_kernel<<<(N + 3) / 4, 256, 0, stream>>>(indptr, csr, al_s3, al_d3, h3,
                                                  b3, out3, N);

  // Pool + FC
  pool_kernel<<<((size_t)N * 64 + 255) / 256, 256, 0, stream>>>(out3, batch,
                                                                sums, N);
  final_kernel<<<1, 256, 0, stream>>>(sums, batch, N, fcW, fcb, out);
}

// Round 2
// 744.218 us; speedup vs baseline: 1.4274x; 1.4274x over previous
//
#include <hip/hip_runtime.h>
#include <hip/hip_bf16.h>
#include <cstdint>

#define NEG_SLOPE 0.2f

typedef __attribute__((ext_vector_type(8))) short bf16x8;
typedef __attribute__((ext_vector_type(4))) float f32x4;

__device__ __forceinline__ float bf2f(uint32_t u) {
  union { float f; uint32_t i; } v;
  v.i = u << 16;
  return v.f;
}
__device__ __forceinline__ ushort f2bf(float f) {
  union { float f; uint32_t i; } v;
  v.f = f;
  uint32_t r = v.i + 0x7FFF + ((v.i >> 16) & 1);  // round-nearest-even
  return (ushort)(r >> 16);
}

// ---------------------------------------------------------------------------
// Cast fp32 -> bf16, 4 elems/thread.
// ---------------------------------------------------------------------------
__global__ void cast_f32_bf16(const float4* __restrict__ in,
                              uint2* __restrict__ out, int n4) {
  int i = blockIdx.x * 256 + threadIdx.x;
  if (i >= n4) return;
  float4 v = in[i];
  uint2 o;
  o.x = (uint32_t)f2bf(v.x) | ((uint32_t)f2bf(v.y) << 16);
  o.y = (uint32_t)f2bf(v.z) | ((uint32_t)f2bf(v.w) << 16);
  out[i] = o;
}

// ---------------------------------------------------------------------------
// Transpose+cast: in [K,N] fp32 -> out [N,K] bf16. Tiny weight matrices.
// ---------------------------------------------------------------------------
__global__ void transpose_cast(const float* __restrict__ in,
                               ushort* __restrict__ out, int K, int N) {
  int idx = blockIdx.x * 256 + threadIdx.x;
  if (idx >= K * N) return;
  int n = idx / K, k = idx - n * K;
  out[idx] = f2bf(in[(size_t)k * N + n]);
}

// ---------------------------------------------------------------------------
// MFMA bf16 GEMM: C[M,N] = A[M,K] @ B[K,N], A row-major bf16, BT = B^T [N,K]
// bf16, C bf16. Block = 4 waves; wave computes 16 rows x 64 cols.
// K % 32 == 0, N % 64 == 0, M % 16 == 0.
// ---------------------------------------------------------------------------
__global__ __launch_bounds__(256) void gemm_mfma(
    const ushort* __restrict__ A, const ushort* __restrict__ BT,
    ushort* __restrict__ C, int M, int N, int K) {
  const int wave = threadIdx.x >> 6;
  const int lane = threadIdx.x & 63;
  const int rt = blockIdx.y * 4 + wave;
  const int r0 = rt * 16;
  if (r0 >= M) return;
  const int n0 = blockIdx.x * 64;
  const int l15 = lane & 15, q = lane >> 4;
  const ushort* Ap = A + (size_t)(r0 + l15) * K + q * 8;
  f32x4 acc[4] = {};
  for (int k0 = 0; k0 < K; k0 += 32) {
    bf16x8 a = *(const bf16x8*)(Ap + k0);
#pragma unroll
    for (int j = 0; j < 4; ++j) {
      const bf16x8 b =
          *(const bf16x8*)(BT + (size_t)(n0 + j * 16 + l15) * K + q * 8 + k0);
      acc[j] = __builtin_amdgcn_mfma_f32_16x16x32_bf16(a, b, acc[j], 0, 0, 0);
    }
  }
#pragma unroll
  for (int j = 0; j < 4; ++j)
#pragma unroll
    for (int r = 0; r < 4; ++r) {
      int row = r0 + q * 4 + r;
      C[(size_t)row * N + n0 + j * 16 + l15] = f2bf(acc[j][r]);
    }
}

// ---------------------------------------------------------------------------
// al_s[n*H+h] = sum_c h[n,h,c]*a_src[h,c];  al_d likewise. One wave per (n,h).
// h is bf16.
// ---------------------------------------------------------------------------
__global__ __launch_bounds__(256) void compute_al(
    const ushort* __restrict__ h, const float* __restrict__ a_src,
    const float* __restrict__ a_dst, float* __restrict__ al_s,
    float* __restrict__ al_d, int nwaves, int H) {
  int w = (blockIdx.x * 256 + threadIdx.x) >> 6;
  int lane = threadIdx.x & 63;
  if (w >= nwaves) return;
  int hh = w % H;
  float v = bf2f(h[(size_t)w * 64 + lane]);
  float vs = v * a_src[hh * 64 + lane];
  float vd = v * a_dst[hh * 64 + lane];
#pragma unroll
  for (int off = 32; off; off >>= 1) {
    vs += __shfl_xor(vs, off);
    vd += __shfl_xor(vd, off);
  }
  if (lane == 0) {
    al_s[w] = vs;
    al_d[w] = vd;
  }
}

// ---------------------------------------------------------------------------
// CSR build
// ---------------------------------------------------------------------------
__global__ void count_kernel(const int* __restrict__ dst, int* __restrict__ cnt,
                             int E) {
  int e = blockIdx.x * 256 + threadIdx.x;
  if (e < E) atomicAdd(&cnt[dst[e]], 1);
}

__global__ void scan_block(const int* __restrict__ in, int* __restrict__ out,
                           int* __restrict__ bsum, int n) {
  __shared__ int sm[256];
  int gid = blockIdx.x * 256 + threadIdx.x;
  int v = (gid < n) ? in[gid] : 0;
  sm[threadIdx.x] = v;
  __syncthreads();
  for (int off = 1; off < 256; off <<= 1) {
    int t = (threadIdx.x >= off) ? sm[threadIdx.x - off] : 0;
    __syncthreads();
    sm[threadIdx.x] += t;
    __syncthreads();
  }
  if (gid < n) out[gid] = sm[threadIdx.x];
  if (threadIdx.x == 255) bsum[blockIdx.x] = sm[255];
}

__global__ void scan_bsum(int* __restrict__ bsum, int nb) {
  __shared__ int sm[256];
  int t = threadIdx.x;
  sm[t] = (t < nb) ? bsum[t] : 0;
  __syncthreads();
  for (int off = 1; off < 256; off <<= 1) {
    int v = (t >= off) ? sm[t - off] : 0;
    __syncthreads();
    sm[t] += v;
    __syncthreads();
  }
  if (t < nb) bsum[t] = sm[t];
}

__global__ void scan_final(const int* __restrict__ inc,
                           const int* __restrict__ bscan,
                           int* __restrict__ indptr, int n) {
  int gid = blockIdx.x * 256 + threadIdx.x;
  if (gid < n) {
    int add = blockIdx.x ? bscan[blockIdx.x - 1] : 0;
    indptr[gid + 1] = inc[gid] + add;
  }
  if (gid == 0) indptr[0] = 0;
}

__global__ void scatter_kernel(const int* __restrict__ src,
                               const int* __restrict__ dst,
                               const int* __restrict__ indptr,
                               int* __restrict__ fill,
                               int* __restrict__ csr_src, int E) {
  int e = blockIdx.x * 256 + threadIdx.x;
  if (e < E) {
    int dd = dst[e];
    int pos = indptr[dd] + atomicAdd(&fill[dd], 1);
    csr_src[pos] = src[e];
  }
}

// ---------------------------------------------------------------------------
// Attention layer 1: H=8, C=64 (512 channels), h1 bf16. One block per node.
// Thread handles channels 2*tid, 2*tid+1 (same head).
// ---------------------------------------------------------------------------
__global__ __launch_bounds__(256) void attn1_kernel(
    const int* __restrict__ indptr, const int* __restrict__ csr_src,
    const float* __restrict__ al_s, const float* __restrict__ al_d,
    const ushort* __restrict__ h1, const float* __restrict__ b1,
    ushort* __restrict__ out1) {
  const int d = blockIdx.x;
  const int tid = threadIdx.x;
  const int start = indptr[d];
  const int deg = indptr[d + 1] - start;
  const int total = deg + 1;  // + self loop

  __shared__ float s_red[256];
  __shared__ float s_ald[8], s_m[8], s_den[8];
  __shared__ float s_alpha[64][8];
  __shared__ int s_srcs[64];

  if (tid < 8) s_ald[tid] = al_d[(size_t)d * 8 + tid];
  __syncthreads();

  const int h = tid & 7;
  const int le = tid >> 3;  // 32 edge-lanes per head
  const float ald = s_ald[h];

  // pass A: per-head max
  float mx = -1e30f;
  for (int e = le; e < total; e += 32) {
    int s = (e < deg) ? csr_src[start + e] : d;
    float v = al_s[(size_t)s * 8 + h] + ald;
    v = (v > 0.f) ? v : NEG_SLOPE * v;
    mx = fmaxf(mx, v);
  }
  s_red[tid] = mx;
  __syncthreads();
  for (int off = 128; off >= 8; off >>= 1) {
    if (tid < off) s_red[tid] = fmaxf(s_red[tid], s_red[tid + off]);
    __syncthreads();
  }
  if (tid < 8) s_m[tid] = s_red[tid];
  __syncthreads();

  // pass B: per-head denom
  const float m = s_m[h];
  float sm = 0.f;
  for (int e = le; e < total; e += 32) {
    int s = (e < deg) ? csr_src[start + e] : d;
    float v = al_s[(size_t)s * 8 + h] + ald;
    v = (v > 0.f) ? v : NEG_SLOPE * v;
    sm += __expf(v - m);
  }
  __syncthreads();
  s_red[tid] = sm;
  __syncthreads();
  for (int off = 128; off >= 8; off >>= 1) {
    if (tid < off) s_red[tid] += s_red[tid + off];
    __syncthreads();
  }
  if (tid < 8) s_den[tid] = 1.f / s_red[tid];
  __syncthreads();

  // pass C: weighted accumulate. thread handles channels 2*tid, 2*tid+1.
  float acc0 = 0.f, acc1 = 0.f;
  const int c0 = tid * 2;
  const int hh0 = c0 >> 6;
  for (int e0 = 0; e0 < total; e0 += 64) {
    int ne = min(64, total - e0);
    for (int i = tid; i < ne * 8; i += 256) {
      int e = i >> 3, hh = i & 7;
      int ge = e0 + e;
      int s = (ge < deg) ? csr_src[start + ge] : d;
      if (hh == 0) s_srcs[e] = s;
      float v = al_s[(size_t)s * 8 + hh] + s_ald[hh];
      v = (v > 0.f) ? v : NEG_SLOPE * v;
      s_alpha[e][hh] = __expf(v - s_m[hh]) * s_den[hh];
    }
    __syncthreads();
    for (int e = 0; e < ne; ++e) {
      const ushort* hrow = h1 + (size_t)s_srcs[e] * 512;
      uint32_t p = *(const uint32_t*)(hrow + c0);
      float a = s_alpha[e][hh0];
      acc0 = fmaf(a, bf2f(p & 0xffffu), acc0);
      acc1 = fmaf(a, bf2f(p >> 16), acc1);
    }
    __syncthreads();
  }
  float v0 = acc0 + b1[c0];
  float v1 = acc1 + b1[c0 + 1];
  v0 = (v0 > 0.f) ? v0 : __expf(v0) - 1.f;
  v1 = (v1 > 0.f) ? v1 : __expf(v1) - 1.f;
  *(uint32_t*)(out1 + (size_t)d * 512 + c0) =
      (uint32_t)f2bf(v0) | ((uint32_t)f2bf(v1) << 16);
}

// ---------------------------------------------------------------------------
// Attention layers 2/3: H=1, C=64, h bf16. One wave per node.
// ---------------------------------------------------------------------------
__global__ __launch_bounds__(256) void attn_h1_kernel(
    const int* __restrict__ indptr, const int* __restrict__ csr_src,
    const float* __restrict__ al_s, const float* __restrict__ al_d,
    const ushort* __restrict__ hin, const float* __restrict__ bias,
    ushort* __restrict__ outp, int Nn) {
  int w = (blockIdx.x * 256 + threadIdx.x) >> 6;
  int lane = threadIdx.x & 63;
  if (w >= Nn) return;
  const int d = w;
  const int start = indptr[d];
  const int deg = indptr[d + 1] - start;
  const int total = deg + 1;
  const float ald = al_d[d];

  float mx = -1e30f;
  for (int e = lane; e < total; e += 64) {
    int s = (e < deg) ? csr_src[start + e] : d;
    float v = al_s[s] + ald;
    v = (v > 0.f) ? v : NEG_SLOPE * v;
    mx = fmaxf(mx, v);
  }
#pragma unroll
  for (int off = 32; off; off >>= 1) mx = fmaxf(mx, __shfl_xor(mx, off));

  float sm = 0.f;
  for (int e = lane; e < total; e += 64) {
    int s = (e < deg) ? csr_src[start + e] : d;
    float v = al_s[s] + ald;
    v = (v > 0.f) ? v : NEG_SLOPE * v;
    sm += __expf(v - mx);
  }
#pragma unroll
  for (int off = 32; off; off >>= 1) sm += __shfl_xor(sm, off);
  const float inv_den = 1.f / sm;

  float acc = 0.f;
  for (int e0 = 0; e0 < total; e0 += 64) {
    int ne = min(64, total - e0);
    int e = e0 + lane;
    float alpha = 0.f;
    int s = d;
    if (e < total) {
      s = (e < deg) ? csr_src[start + e] : d;
      float v = al_s[s] + ald;
      v = (v > 0.f) ? v : NEG_SLOPE * v;
      alpha = __expf(v - mx) * inv_den;
    }
    for (int j = 0; j < ne; ++j) {
      float a = __shfl(alpha, j);
      int ss = __shfl(s, j);
      acc = fmaf(a, bf2f(hin[(size_t)ss * 64 + lane]), acc);
    }
  }
  float v = acc + bias[lane];
  v = (v > 0.f) ? v : __expf(v) - 1.f;
  outp[(size_t)d * 64 + lane] = f2bf(v);
}

// ---------------------------------------------------------------------------
// Global mean pool (sum part) via atomics; out3 bf16.
// ---------------------------------------------------------------------------
__global__ void pool_kernel(const ushort* __restrict__ out3,
                            const int* __restrict__ batch,
                            float* __restrict__ sums, int Nn) {
  int idx = blockIdx.x * 256 + threadIdx.x;
  if (idx >= Nn * 64) return;
  int n = idx >> 6, c = idx & 63;
  atomicAdd(&sums[batch[n] * 64 + c], bf2f(out3[idx]));
}

__global__ __launch_bounds__(256) void final_kernel(
    const float* __restrict__ sums, const int* __restrict__ batch, int Nn,
    const float* __restrict__ fcW, const float* __restrict__ fcb,
    float* __restrict__ out) {
  __shared__ int lb[65];
  __shared__ float inv_cnt[64];
  int tid = threadIdx.x;
  if (tid <= 64) {
    int lo = 0, hi = Nn;
    while (lo < hi) {
      int mid = (lo + hi) >> 1;
      if (batch[mid] < tid) lo = mid + 1; else hi = mid;
    }
    lb[tid] = lo;
  }
  __syncthreads();
  if (tid < 64) inv_cnt[tid] = 1.f / fmaxf((float)(lb[tid + 1] - lb[tid]), 1.f);
  __syncthreads();
  for (int i = tid; i < 64 * 10; i += 256) {
    int g = i / 10, o = i % 10;
    float acc = fcb[o];
    float inv = inv_cnt[g];
    for (int c = 0; c < 64; ++c)
      acc = fmaf(sums[g * 64 + c] * inv, fcW[c * 10 + o], acc);
    out[i] = acc;
  }
}

// ---------------------------------------------------------------------------
extern "C" void kernel_launch(void* const* d_in, const int* in_sizes, int n_in,
                              void* d_out, int out_size, void* d_ws,
                              size_t ws_size, hipStream_t stream) {
  const float* x = (const float*)d_in[0];
  const int* ei = (const int*)d_in[1];
  const int* batch = (const int*)d_in[2];
  const float* W1 = (const float*)d_in[3];
  const float* a1s = (const float*)d_in[4];
  const float* a1d = (const float*)d_in[5];
  const float* b1 = (const float*)d_in[6];
  const float* W2 = (const float*)d_in[7];
  const float* a2s = (const float*)d_in[8];
  const float* a2d = (const float*)d_in[9];
  const float* b2 = (const float*)d_in[10];
  const float* W3 = (const float*)d_in[11];
  const float* a3s = (const float*)d_in[12];
  const float* a3d = (const float*)d_in[13];
  const float* b3 = (const float*)d_in[14];
  const float* fcW = (const float*)d_in[15];
  const float* fcb = (const float*)d_in[16];
  float* out = (float*)d_out;

  const int N = in_sizes[0] / 128;  // 50000
  const int E = in_sizes[1] / 2;    // 800000
  const int* srcp = ei;
  const int* dstp = ei + E;

  // --- workspace layout ---
  char* ws = (char*)d_ws;
  size_t off = 0;
  auto alloc = [&](size_t bytes) -> void* {
    off = (off + 255) & ~(size_t)255;
    void* p = ws + off;
    off += bytes;
    return p;
  };
  ushort* x_bf = (ushort*)alloc((size_t)N * 128 * 2);
  ushort* W1T = (ushort*)alloc(512 * 128 * 2);
  ushort* W2T = (ushort*)alloc(64 * 512 * 2);
  ushort* W3T = (ushort*)alloc(64 * 64 * 2);
  ushort* h1 = (ushort*)alloc((size_t)N * 512 * 2);  // reused: h2/out2/h3/out3
  ushort* out1 = (ushort*)alloc((size_t)N * 512 * 2);
  float* al_s1 = (float*)alloc((size_t)N * 8 * 4);
  float* al_d1 = (float*)alloc((size_t)N * 8 * 4);
  float* al_s2 = (float*)alloc((size_t)N * 4);
  float* al_d2 = (float*)alloc((size_t)N * 4);
  float* al_s3 = (float*)alloc((size_t)N * 4);
  float* al_d3 = (float*)alloc((size_t)N * 4);
  int* cnt = (int*)alloc((size_t)N * 4);
  int* fill = (int*)alloc((size_t)N * 4);
  int* indptr = (int*)alloc((size_t)(N + 1) * 4);
  int* csr = (int*)alloc((size_t)E * 4);
  int* incbuf = (int*)alloc((size_t)N * 4);
  int* bsum = (int*)alloc(1024 * 4);
  float* sums = (float*)alloc(64 * 64 * 4);

  // aliases into the (dead-after-attn1) h1 region
  ushort* h2 = h1;
  ushort* out2 = h1 + (size_t)N * 64;
  ushort* h3 = h1 + (size_t)2 * N * 64;
  ushort* out3 = h1 + (size_t)3 * N * 64;

  hipMemsetAsync(cnt, 0, (size_t)N * 4, stream);
  hipMemsetAsync(fill, 0, (size_t)N * 4, stream);
  hipMemsetAsync(sums, 0, 64 * 64 * 4, stream);

  const int scan_blocks = (N + 255) / 256;
  const int row_blocks = (N / 16 + 3) / 4;  // 3125 wave-tiles / 4 per block

  // casts
  cast_f32_bf16<<<((size_t)N * 128 / 4 + 255) / 256, 256, 0, stream>>>(
      (const float4*)x, (uint2*)x_bf, N * 128 / 4);
  transpose_cast<<<(128 * 512 + 255) / 256, 256, 0, stream>>>(W1, W1T, 128,
                                                              512);
  transpose_cast<<<(512 * 64 + 255) / 256, 256, 0, stream>>>(W2, W2T, 512, 64);
  transpose_cast<<<(64 * 64 + 255) / 256, 256, 0, stream>>>(W3, W3T, 64, 64);

  // GEMM1: h1 = x @ W1   [N,128]@[128,512]
  gemm_mfma<<<dim3(512 / 64, row_blocks), 256, 0, stream>>>(x_bf, W1T, h1, N,
                                                            512, 128);
  compute_al<<<(N * 8 + 3) / 4, 256, 0, stream>>>(h1, a1s, a1d, al_s1, al_d1,
                                                  N * 8, 8);
  // CSR build
  count_kernel<<<(E + 255) / 256, 256, 0, stream>>>(dstp, cnt, E);
  scan_block<<<scan_blocks, 256, 0, stream>>>(cnt, incbuf, bsum, N);
  scan_bsum<<<1, 256, 0, stream>>>(bsum, scan_blocks);
  scan_final<<<scan_blocks, 256, 0, stream>>>(incbuf, bsum, indptr, N);
  scatter_kernel<<<(E + 255) / 256, 256, 0, stream>>>(srcp, dstp, indptr, fill,
                                                      csr, E);
  // Layer 1 attention + bias + ELU
  attn1_kernel<<<N, 256, 0, stream>>>(indptr, csr, al_s1, al_d1, h1, b1, out1);

  // Layer 2
  gemm_mfma<<<dim3(1, row_blocks), 256, 0, stream>>>(out1, W2T, h2, N, 64, 512);
  compute_al<<<(N + 3) / 4, 256, 0, stream>>>(h2, a2s, a2d, al_s2, al_d2, N, 1);
  attn_h1_kernel<<<(N + 3) / 4, 256, 0, stream>>>(indptr, csr, al_s2, al_d2, h2,
                                                  b2, out2, N);

  // Layer 3
  gemm_mfma<<<dim3(1, row_blocks), 256, 0, stream>>>(out2, W3T, h3, N, 64, 64);
  compute_al<<<(N + 3) / 4, 256, 0, stream>>>(h3, a3s, a3d, al_s3, al_d3, N, 1);
  attn_h1_kernel<<<(N + 3) / 4, 256, 0, stream>>>(indptr, csr, al_s3, al_d3, h3,
                                                  b3, out3, N);

  // Pool + FC
  pool_kernel<<<((size_t)N * 64 + 255) / 256, 256, 0, stream>>>(out3, batch,
                                                                sums, N);
  final_kernel<<<1, 256, 0, stream>>>(sums, batch, N, fcW, fcb, out);
}

// Round 3
// 681.835 us; speedup vs baseline: 1.5580x; 1.0915x over previous
//
#include <hip/hip_runtime.h>
#include <hip/hip_bf16.h>
#include <cstdint>

#define NEG_SLOPE 0.2f

typedef __attribute__((ext_vector_type(8))) short bf16x8;
typedef __attribute__((ext_vector_type(4))) float f32x4;

__device__ __forceinline__ float bf2f(uint32_t u) {
  union { float f; uint32_t i; } v;
  v.i = u << 16;
  return v.f;
}
__device__ __forceinline__ float lo16(uint32_t u) {
  union { float f; uint32_t i; } v;
  v.i = u << 16;
  return v.f;
}
__device__ __forceinline__ float hi16(uint32_t u) {
  union { float f; uint32_t i; } v;
  v.i = u & 0xffff0000u;
  return v.f;
}
__device__ __forceinline__ ushort f2bf(float f) {
  union { float f; uint32_t i; } v;
  v.f = f;
  uint32_t r = v.i + 0x7FFF + ((v.i >> 16) & 1);  // round-nearest-even
  return (ushort)(r >> 16);
}

// ---------------------------------------------------------------------------
// prep: cast x -> bf16 (vectorized), transpose+cast W1/W2/W3, CSR count pass.
// ---------------------------------------------------------------------------
__global__ void prep_kernel(const float4* __restrict__ x,
                            uint2* __restrict__ x_bf, int n_x4,
                            const float* __restrict__ W1,
                            ushort* __restrict__ W1T,
                            const float* __restrict__ W2,
                            ushort* __restrict__ W2T,
                            const float* __restrict__ W3,
                            ushort* __restrict__ W3T,
                            const int* __restrict__ dst, int* __restrict__ cnt,
                            int E) {
  int i = blockIdx.x * 256 + threadIdx.x;
  const int r0 = n_x4;
  const int r1 = r0 + 512 * 128;
  const int r2 = r1 + 64 * 512;
  const int r3 = r2 + 64 * 64;
  const int r4 = r3 + E;
  if (i < r0) {
    float4 v = x[i];
    uint2 o;
    o.x = (uint32_t)f2bf(v.x) | ((uint32_t)f2bf(v.y) << 16);
    o.y = (uint32_t)f2bf(v.z) | ((uint32_t)f2bf(v.w) << 16);
    x_bf[i] = o;
  } else if (i < r1) {
    int idx = i - r0;
    int n = idx >> 7, k = idx & 127;
    W1T[idx] = f2bf(W1[(size_t)k * 512 + n]);
  } else if (i < r2) {
    int idx = i - r1;
    int n = idx >> 9, k = idx & 511;
    W2T[idx] = f2bf(W2[(size_t)k * 64 + n]);
  } else if (i < r3) {
    int idx = i - r2;
    int n = idx >> 6, k = idx & 63;
    W3T[idx] = f2bf(W3[(size_t)k * 64 + n]);
  } else if (i < r4) {
    atomicAdd(&cnt[dst[i - r3]], 1);
  }
}

// ---------------------------------------------------------------------------
// GEMM1 + fused al: C[M,512] = A[M,128] @ W1 (BT=[512,128]).
// Block = 4 waves; wave = 16 rows x 128 cols (j=0..7). grid=(4, M/64).
// Epilogue computes al_s1/al_d1 for the 2 heads this wave covers.
// ---------------------------------------------------------------------------
__global__ __launch_bounds__(256) void gemm1_al(
    const ushort* __restrict__ A, const ushort* __restrict__ BT,
    ushort* __restrict__ C, const float* __restrict__ a1s,
    const float* __restrict__ a1d, float* __restrict__ al_s,
    float* __restrict__ al_d, int M) {
  const int K = 128;
  const int wave = threadIdx.x >> 6;
  const int lane = threadIdx.x & 63;
  const int rt = blockIdx.y * 4 + wave;
  const int r0 = rt * 16;
  if (r0 >= M) return;
  const int bx = blockIdx.x;
  const int n0 = bx * 128;
  const int l15 = lane & 15, q = lane >> 4;
  const ushort* Ap = A + (size_t)(r0 + l15) * K + q * 8;
  f32x4 acc[8] = {};
  for (int k0 = 0; k0 < K; k0 += 32) {
    bf16x8 a = *(const bf16x8*)(Ap + k0);
#pragma unroll
    for (int j = 0; j < 8; ++j) {
      const bf16x8 b =
          *(const bf16x8*)(BT + (size_t)(n0 + j * 16 + l15) * K + q * 8 + k0);
      acc[j] = __builtin_amdgcn_mfma_f32_16x16x32_bf16(a, b, acc[j], 0, 0, 0);
    }
  }
  // store C
#pragma unroll
  for (int j = 0; j < 8; ++j)
#pragma unroll
    for (int r = 0; r < 4; ++r) {
      int row = r0 + q * 4 + r;
      C[(size_t)row * 512 + n0 + j * 16 + l15] = f2bf(acc[j][r]);
    }
  // fused al: heads bx*2, bx*2+1
  float als_p[2][4] = {{0.f}};
  float ald_p[2][4] = {{0.f}};
#pragma unroll
  for (int j = 0; j < 8; ++j) {
    int head = bx * 2 + (j >> 2);
    int cih = (j & 3) * 16 + l15;
    float wsc = a1s[head * 64 + cih];
    float wdc = a1d[head * 64 + cih];
#pragma unroll
    for (int r = 0; r < 4; ++r) {
      als_p[j >> 2][r] = fmaf(acc[j][r], wsc, als_p[j >> 2][r]);
      ald_p[j >> 2][r] = fmaf(acc[j][r], wdc, ald_p[j >> 2][r]);
    }
  }
#pragma unroll
  for (int g = 0; g < 2; ++g)
#pragma unroll
    for (int r = 0; r < 4; ++r) {
      float vs = als_p[g][r], vd = ald_p[g][r];
#pragma unroll
      for (int off = 1; off < 16; off <<= 1) {
        vs += __shfl_xor(vs, off);
        vd += __shfl_xor(vd, off);
      }
      if (l15 == 0) {
        int row = r0 + q * 4 + r;
        al_s[(size_t)row * 8 + bx * 2 + g] = vs;
        al_d[(size_t)row * 8 + bx * 2 + g] = vd;
      }
    }
}

// ---------------------------------------------------------------------------
// GEMM (N=64) + fused al (H=1): C[M,64] = A[M,K] @ BT[64,K].
// Block = 4 waves; wave = 16 rows x 64 cols. grid=(1, M/64).
// ---------------------------------------------------------------------------
__global__ __launch_bounds__(256) void gemm_n64_al(
    const ushort* __restrict__ A, const ushort* __restrict__ BT,
    ushort* __restrict__ C, const float* __restrict__ asrc,
    const float* __restrict__ adst, float* __restrict__ al_s,
    float* __restrict__ al_d, int M, int K) {
  const int wave = threadIdx.x >> 6;
  const int lane = threadIdx.x & 63;
  const int rt = blockIdx.y * 4 + wave;
  const int r0 = rt * 16;
  if (r0 >= M) return;
  const int l15 = lane & 15, q = lane >> 4;
  const ushort* Ap = A + (size_t)(r0 + l15) * K + q * 8;
  f32x4 acc[4] = {};
  for (int k0 = 0; k0 < K; k0 += 32) {
    bf16x8 a = *(const bf16x8*)(Ap + k0);
#pragma unroll
    for (int j = 0; j < 4; ++j) {
      const bf16x8 b =
          *(const bf16x8*)(BT + (size_t)(j * 16 + l15) * K + q * 8 + k0);
      acc[j] = __builtin_amdgcn_mfma_f32_16x16x32_bf16(a, b, acc[j], 0, 0, 0);
    }
  }
#pragma unroll
  for (int j = 0; j < 4; ++j)
#pragma unroll
    for (int r = 0; r < 4; ++r) {
      int row = r0 + q * 4 + r;
      C[(size_t)row * 64 + j * 16 + l15] = f2bf(acc[j][r]);
    }
  float als_p[4] = {0.f, 0.f, 0.f, 0.f};
  float ald_p[4] = {0.f, 0.f, 0.f, 0.f};
#pragma unroll
  for (int j = 0; j < 4; ++j) {
    float wsc = asrc[j * 16 + l15];
    float wdc = adst[j * 16 + l15];
#pragma unroll
    for (int r = 0; r < 4; ++r) {
      als_p[r] = fmaf(acc[j][r], wsc, als_p[r]);
      ald_p[r] = fmaf(acc[j][r], wdc, ald_p[r]);
    }
  }
#pragma unroll
  for (int r = 0; r < 4; ++r) {
    float vs = als_p[r], vd = ald_p[r];
#pragma unroll
    for (int off = 1; off < 16; off <<= 1) {
      vs += __shfl_xor(vs, off);
      vd += __shfl_xor(vd, off);
    }
    if (l15 == 0) {
      int row = r0 + q * 4 + r;
      al_s[row] = vs;
      al_d[row] = vd;
    }
  }
}

// ---------------------------------------------------------------------------
// CSR scan + scatter
// ---------------------------------------------------------------------------
__global__ void scan_block(const int* __restrict__ in, int* __restrict__ out,
                           int* __restrict__ bsum, int n) {
  __shared__ int sm[256];
  int gid = blockIdx.x * 256 + threadIdx.x;
  int v = (gid < n) ? in[gid] : 0;
  sm[threadIdx.x] = v;
  __syncthreads();
  for (int off = 1; off < 256; off <<= 1) {
    int t = (threadIdx.x >= off) ? sm[threadIdx.x - off] : 0;
    __syncthreads();
    sm[threadIdx.x] += t;
    __syncthreads();
  }
  if (gid < n) out[gid] = sm[threadIdx.x];
  if (threadIdx.x == 255) bsum[blockIdx.x] = sm[255];
}

__global__ void scan_bsum(int* __restrict__ bsum, int nb) {
  __shared__ int sm[256];
  int t = threadIdx.x;
  sm[t] = (t < nb) ? bsum[t] : 0;
  __syncthreads();
  for (int off = 1; off < 256; off <<= 1) {
    int v = (t >= off) ? sm[t - off] : 0;
    __syncthreads();
    sm[t] += v;
    __syncthreads();
  }
  if (t < nb) bsum[t] = sm[t];
}

__global__ void scan_final(const int* __restrict__ inc,
                           const int* __restrict__ bscan,
                           int* __restrict__ indptr, int n) {
  int gid = blockIdx.x * 256 + threadIdx.x;
  if (gid < n) {
    int add = blockIdx.x ? bscan[blockIdx.x - 1] : 0;
    indptr[gid + 1] = inc[gid] + add;
  }
  if (gid == 0) indptr[0] = 0;
}

__global__ void scatter_kernel(const int* __restrict__ src,
                               const int* __restrict__ dst,
                               const int* __restrict__ indptr,
                               int* __restrict__ fill,
                               int* __restrict__ csr_src, int E) {
  int e = blockIdx.x * 256 + threadIdx.x;
  if (e < E) {
    int dd = dst[e];
    int pos = indptr[dd] + atomicAdd(&fill[dd], 1);
    csr_src[pos] = src[e];
  }
}

// ---------------------------------------------------------------------------
// Attention layer 1: H=8, C=64, h1 bf16. One block (256 thr) per node.
// Accumulate uses UNNORMALIZED alphas (wave-per-edge, dwordx4 row loads);
// denominator applied at the end.
// ---------------------------------------------------------------------------
__global__ __launch_bounds__(256) void attn1_kernel(
    const int* __restrict__ indptr, const int* __restrict__ csr_src,
    const float* __restrict__ al_s, const float* __restrict__ al_d,
    const ushort* __restrict__ h1, const float* __restrict__ b1,
    ushort* __restrict__ out1) {
  const int d = blockIdx.x;
  const int tid = threadIdx.x;
  const int w = tid >> 6;
  const int l = tid & 63;
  const int start = indptr[d];
  const int deg = indptr[d + 1] - start;
  const int total = deg + 1;  // + self loop

  __shared__ float s_alpha[256][9];  // stride 9: conflict-free
  __shared__ int s_srcs[256];
  __shared__ float s_accbuf[4][512];
  __shared__ float s_stat[4][8];
  __shared__ float s_m[8];
  __shared__ float s_inv[8];

  // all-head ald into regs
  float ald[8];
  {
    const float4* p = (const float4*)(al_d + (size_t)d * 8);
    float4 a0 = p[0], a1 = p[1];
    ald[0] = a0.x; ald[1] = a0.y; ald[2] = a0.z; ald[3] = a0.w;
    ald[4] = a1.x; ald[5] = a1.y; ald[6] = a1.z; ald[7] = a1.w;
  }

  // pass A: per-head max. h = tid&7, edge slot = tid>>3 (32 slots).
  {
    const int h = tid & 7, el = tid >> 3;
    float mx = -1e30f;
    for (int e = el; e < total; e += 32) {
      int s = (e < deg) ? csr_src[start + e] : d;
      float v = al_s[(size_t)s * 8 + h] + ald[h];
      v = fmaxf(v, NEG_SLOPE * v);
      mx = fmaxf(mx, v);
    }
    mx = fmaxf(mx, __shfl_xor(mx, 8));
    mx = fmaxf(mx, __shfl_xor(mx, 16));
    mx = fmaxf(mx, __shfl_xor(mx, 32));
    if (l < 8) s_stat[w][l] = mx;  // lane l has h == l&7 == l
  }
  __syncthreads();
  if (tid < 8)
    s_m[tid] = fmaxf(fmaxf(s_stat[0][tid], s_stat[1][tid]),
                     fmaxf(s_stat[2][tid], s_stat[3][tid]));
  __syncthreads();
  float m[8];
#pragma unroll
  for (int k = 0; k < 8; ++k) m[k] = s_m[k];

  const int head = l >> 3;  // head for this lane's channel block
  float acc[8] = {0.f, 0.f, 0.f, 0.f, 0.f, 0.f, 0.f, 0.f};
  float den[8] = {0.f, 0.f, 0.f, 0.f, 0.f, 0.f, 0.f, 0.f};

  for (int e0 = 0; e0 < total; e0 += 256) {
    // alpha stage: thread t handles edge e0+t, all 8 heads (unnormalized)
    int ge = e0 + tid;
    if (ge < total) {
      int s = (ge < deg) ? csr_src[start + ge] : d;
      s_srcs[tid] = s;
      const float4* ap = (const float4*)(al_s + (size_t)s * 8);
      float4 a0 = ap[0], a1 = ap[1];
      float av[8] = {a0.x, a0.y, a0.z, a0.w, a1.x, a1.y, a1.z, a1.w};
#pragma unroll
      for (int k = 0; k < 8; ++k) {
        float v = av[k] + ald[k];
        v = fmaxf(v, NEG_SLOPE * v);
        float u = __expf(v - m[k]);
        s_alpha[tid][k] = u;
        den[k] += u;
      }
    }
    __syncthreads();
    // accumulate: wave per edge, lane covers 8 channels l*8..l*8+7
    int ne = min(256, total - e0);
    for (int e = w; e < ne; e += 4) {
      int s = s_srcs[e];
      float a = s_alpha[e][head];
      const uint4 u = *(const uint4*)(h1 + (size_t)s * 512 + l * 8);
      acc[0] = fmaf(a, lo16(u.x), acc[0]);
      acc[1] = fmaf(a, hi16(u.x), acc[1]);
      acc[2] = fmaf(a, lo16(u.y), acc[2]);
      acc[3] = fmaf(a, hi16(u.y), acc[3]);
      acc[4] = fmaf(a, lo16(u.z), acc[4]);
      acc[5] = fmaf(a, hi16(u.z), acc[5]);
      acc[6] = fmaf(a, lo16(u.w), acc[6]);
      acc[7] = fmaf(a, hi16(u.w), acc[7]);
    }
    __syncthreads();
  }

  // stash per-wave partial sums
#pragma unroll
  for (int k = 0; k < 8; k += 4)
    *(float4*)&s_accbuf[w][l * 8 + k] =
        make_float4(acc[k], acc[k + 1], acc[k + 2], acc[k + 3]);
  // reduce denominator across lanes, then waves
#pragma unroll
  for (int k = 0; k < 8; ++k) {
    float v = den[k];
#pragma unroll
    for (int off = 1; off < 64; off <<= 1) v += __shfl_xor(v, off);
    den[k] = v;
  }
  if (l == 0) {
#pragma unroll
    for (int k = 0; k < 8; ++k) s_stat[w][k] = den[k];
  }
  __syncthreads();
  if (tid < 8)
    s_inv[tid] =
        1.f / (s_stat[0][tid] + s_stat[1][tid] + s_stat[2][tid] + s_stat[3][tid]);
  __syncthreads();

  // final: thread t -> channels 2t, 2t+1
  const int c0 = tid * 2;
  float f0 = s_accbuf[0][c0] + s_accbuf[1][c0] + s_accbuf[2][c0] +
             s_accbuf[3][c0];
  float f1 = s_accbuf[0][c0 + 1] + s_accbuf[1][c0 + 1] + s_accbuf[2][c0 + 1] +
             s_accbuf[3][c0 + 1];
  float inv = s_inv[c0 >> 6];
  float v0 = f0 * inv + b1[c0];
  float v1 = f1 * inv + b1[c0 + 1];
  v0 = (v0 > 0.f) ? v0 : __expf(v0) - 1.f;
  v1 = (v1 > 0.f) ? v1 : __expf(v1) - 1.f;
  *(uint32_t*)(out1 + (size_t)d * 512 + c0) =
      (uint32_t)f2bf(v0) | ((uint32_t)f2bf(v1) << 16);
}

// ---------------------------------------------------------------------------
// Attention layers 2/3: H=1, C=64, h bf16. One wave per node.
// ---------------------------------------------------------------------------
__global__ __launch_bounds__(256) void attn_h1_kernel(
    const int* __restrict__ indptr, const int* __restrict__ csr_src,
    const float* __restrict__ al_s, const float* __restrict__ al_d,
    const ushort* __restrict__ hin, const float* __restrict__ bias,
    ushort* __restrict__ outp, int Nn) {
  int w = (blockIdx.x * 256 + threadIdx.x) >> 6;
  int lane = threadIdx.x & 63;
  if (w >= Nn) return;
  const int d = w;
  const int start = indptr[d];
  const int deg = indptr[d + 1] - start;
  const int total = deg + 1;
  const float ald = al_d[d];

  float mx = -1e30f;
  for (int e = lane; e < total; e += 64) {
    int s = (e < deg) ? csr_src[start + e] : d;
    float v = al_s[s] + ald;
    v = fmaxf(v, NEG_SLOPE * v);
    mx = fmaxf(mx, v);
  }
#pragma unroll
  for (int off = 32; off; off >>= 1) mx = fmaxf(mx, __shfl_xor(mx, off));

  float sm = 0.f;
  for (int e = lane; e < total; e += 64) {
    int s = (e < deg) ? csr_src[start + e] : d;
    float v = al_s[s] + ald;
    v = fmaxf(v, NEG_SLOPE * v);
    sm += __expf(v - mx);
  }
#pragma unroll
  for (int off = 32; off; off >>= 1) sm += __shfl_xor(sm, off);
  const float inv_den = 1.f / sm;

  float acc = 0.f;
  for (int e0 = 0; e0 < total; e0 += 64) {
    int ne = min(64, total - e0);
    int e = e0 + lane;
    float alpha = 0.f;
    int s = d;
    if (e < total) {
      s = (e < deg) ? csr_src[start + e] : d;
      float v = al_s[s] + ald;
      v = fmaxf(v, NEG_SLOPE * v);
      alpha = __expf(v - mx) * inv_den;
    }
    for (int j = 0; j < ne; ++j) {
      float a = __shfl(alpha, j);
      int ss = __shfl(s, j);
      acc = fmaf(a, bf2f(hin[(size_t)ss * 64 + lane]), acc);
    }
  }
  float v = acc + bias[lane];
  v = (v > 0.f) ? v : __expf(v) - 1.f;
  outp[(size_t)d * 64 + lane] = f2bf(v);
}

// ---------------------------------------------------------------------------
// Global mean pool (sum part) via atomics; out3 bf16.
// ---------------------------------------------------------------------------
__global__ void pool_kernel(const ushort* __restrict__ out3,
                            const int* __restrict__ batch,
                            float* __restrict__ sums, int Nn) {
  int idx = blockIdx.x * 256 + threadIdx.x;
  if (idx >= Nn * 64) return;
  int n = idx >> 6, c = idx & 63;
  atomicAdd(&sums[batch[n] * 64 + c], bf2f(out3[idx]));
}

__global__ __launch_bounds__(256) void final_kernel(
    const float* __restrict__ sums, const int* __restrict__ batch, int Nn,
    const float* __restrict__ fcW, const float* __restrict__ fcb,
    float* __restrict__ out) {
  __shared__ int lb[65];
  __shared__ float inv_cnt[64];
  int tid = threadIdx.x;
  if (tid <= 64) {
    int lo = 0, hi = Nn;
    while (lo < hi) {
      int mid = (lo + hi) >> 1;
      if (batch[mid] < tid) lo = mid + 1; else hi = mid;
    }
    lb[tid] = lo;
  }
  __syncthreads();
  if (tid < 64) inv_cnt[tid] = 1.f / fmaxf((float)(lb[tid + 1] - lb[tid]), 1.f);
  __syncthreads();
  for (int i = tid; i < 64 * 10; i += 256) {
    int g = i / 10, o = i % 10;
    float acc = fcb[o];
    float inv = inv_cnt[g];
    for (int c = 0; c < 64; ++c)
      acc = fmaf(sums[g * 64 + c] * inv, fcW[c * 10 + o], acc);
    out[i] = acc;
  }
}

// ---------------------------------------------------------------------------
extern "C" void kernel_launch(void* const* d_in, const int* in_sizes, int n_in,
                              void* d_out, int out_size, void* d_ws,
                              size_t ws_size, hipStream_t stream) {
  const float* x = (const float*)d_in[0];
  const int* ei = (const int*)d_in[1];
  const int* batch = (const int*)d_in[2];
  const float* W1 = (const float*)d_in[3];
  const float* a1s = (const float*)d_in[4];
  const float* a1d = (const float*)d_in[5];
  const float* b1 = (const float*)d_in[6];
  const float* W2 = (const float*)d_in[7];
  const float* a2s = (const float*)d_in[8];
  const float* a2d = (const float*)d_in[9];
  const float* b2 = (const float*)d_in[10];
  const float* W3 = (const float*)d_in[11];
  const float* a3s = (const float*)d_in[12];
  const float* a3d = (const float*)d_in[13];
  const float* b3 = (const float*)d_in[14];
  const float* fcW = (const float*)d_in[15];
  const float* fcb = (const float*)d_in[16];
  float* out = (float*)d_out;

  const int N = in_sizes[0] / 128;  // 50000
  const int E = in_sizes[1] / 2;    // 800000
  const int* srcp = ei;
  const int* dstp = ei + E;

  // --- workspace layout ---
  char* ws = (char*)d_ws;
  size_t off = 0;
  auto alloc = [&](size_t bytes) -> void* {
    off = (off + 255) & ~(size_t)255;
    void* p = ws + off;
    off += bytes;
    return p;
  };
  ushort* x_bf = (ushort*)alloc((size_t)N * 128 * 2);
  ushort* W1T = (ushort*)alloc(512 * 128 * 2);
  ushort* W2T = (ushort*)alloc(64 * 512 * 2);
  ushort* W3T = (ushort*)alloc(64 * 64 * 2);
  ushort* h1 = (ushort*)alloc((size_t)N * 512 * 2);  // reused: h2/out2/h3/out3
  ushort* out1 = (ushort*)alloc((size_t)N * 512 * 2);
  float* al_s1 = (float*)alloc((size_t)N * 8 * 4);
  float* al_d1 = (float*)alloc((size_t)N * 8 * 4);
  float* al_s2 = (float*)alloc((size_t)N * 4);
  float* al_d2 = (float*)alloc((size_t)N * 4);
  float* al_s3 = (float*)alloc((size_t)N * 4);
  float* al_d3 = (float*)alloc((size_t)N * 4);
  int* cnt = (int*)alloc((size_t)N * 4);
  int* fill = (int*)alloc((size_t)N * 4);
  int* indptr = (int*)alloc((size_t)(N + 1) * 4);
  int* csr = (int*)alloc((size_t)E * 4);
  int* incbuf = (int*)alloc((size_t)N * 4);
  int* bsum = (int*)alloc(1024 * 4);
  float* sums = (float*)alloc(64 * 64 * 4);

  // aliases into the (dead-after-attn1) h1 region
  ushort* h2 = h1;
  ushort* out2 = h1 + (size_t)N * 64;
  ushort* h3 = h1 + (size_t)2 * N * 64;
  ushort* out3 = h1 + (size_t)3 * N * 64;

  hipMemsetAsync(cnt, 0, (size_t)N * 4, stream);
  hipMemsetAsync(fill, 0, (size_t)N * 4, stream);
  hipMemsetAsync(sums, 0, 64 * 64 * 4, stream);

  const int scan_blocks = (N + 255) / 256;
  const int row_blocks = (N / 16 + 3) / 4;

  // prep: x cast + weight transposes + CSR count
  const int n_x4 = N * 128 / 4;
  const int prep_total = n_x4 + 512 * 128 + 64 * 512 + 64 * 64 + E;
  prep_kernel<<<(prep_total + 255) / 256, 256, 0, stream>>>(
      (const float4*)x, (uint2*)x_bf, n_x4, W1, W1T, W2, W2T, W3, W3T, dstp,
      cnt, E);

  // GEMM1 + al1
  gemm1_al<<<dim3(4, row_blocks), 256, 0, stream>>>(x_bf, W1T, h1, a1s, a1d,
                                                    al_s1, al_d1, N);
  // CSR build
  scan_block<<<scan_blocks, 256, 0, stream>>>(cnt, incbuf, bsum, N);
  scan_bsum<<<1, 256, 0, stream>>>(bsum, scan_blocks);
  scan_final<<<scan_blocks, 256, 0, stream>>>(incbuf, bsum, indptr, N);
  scatter_kernel<<<(E + 255) / 256, 256, 0, stream>>>(srcp, dstp, indptr, fill,
                                                      csr, E);
  // Layer 1 attention + bias + ELU
  attn1_kernel<<<N, 256, 0, stream>>>(indptr, csr, al_s1, al_d1, h1, b1, out1);

  // Layer 2
  gemm_n64_al<<<dim3(1, row_blocks), 256, 0, stream>>>(out1, W2T, h2, a2s, a2d,
                                                       al_s2, al_d2, N, 512);
  attn_h1_kernel<<<(N + 3) / 4, 256, 0, stream>>>(indptr, csr, al_s2, al_d2, h2,
                                                  b2, out2, N);

  // Layer 3
  gemm_n64_al<<<dim3(1, row_blocks), 256, 0, stream>>>(out2, W3T, h3, a3s, a3d,
                                                       al_s3, al_d3, N, 64);
  attn_h1_kernel<<<(N + 3) / 4, 256, 0, stream>>>(indptr, csr, al_s3, al_d3, h3,
                                                  b3, out3, N);

  // Pool + FC
  pool_kernel<<<((size_t)N * 64 + 255) / 256, 256, 0, stream>>>(out3, batch,
                                                                sums, N);
  final_kernel<<<1, 256, 0, stream>>>(sums, batch, N, fcW, fcb, out);
}

// Round 4
// 590.080 us; speedup vs baseline: 1.8003x; 1.1555x over previous
//
#include <hip/hip_runtime.h>
#include <hip/hip_bf16.h>
#include <cstdint>

#define NEG_SLOPE 0.2f

typedef __attribute__((ext_vector_type(8))) short bf16x8;
typedef __attribute__((ext_vector_type(4))) float f32x4;

__device__ __forceinline__ float bf2f(uint32_t u) {
  union { float f; uint32_t i; } v;
  v.i = u << 16;
  return v.f;
}
__device__ __forceinline__ float lo16(uint32_t u) {
  union { float f; uint32_t i; } v;
  v.i = u << 16;
  return v.f;
}
__device__ __forceinline__ float hi16(uint32_t u) {
  union { float f; uint32_t i; } v;
  v.i = u & 0xffff0000u;
  return v.f;
}
__device__ __forceinline__ ushort f2bf(float f) {
  union { float f; uint32_t i; } v;
  v.f = f;
  uint32_t r = v.i + 0x7FFF + ((v.i >> 16) & 1);  // round-nearest-even
  return (ushort)(r >> 16);
}

// ---------------------------------------------------------------------------
// prep: cast x -> bf16 (vectorized), transpose+cast W1/W2/W3, CSR count pass.
// ---------------------------------------------------------------------------
__global__ void prep_kernel(const float4* __restrict__ x,
                            uint2* __restrict__ x_bf, int n_x4,
                            const float* __restrict__ W1,
                            ushort* __restrict__ W1T,
                            const float* __restrict__ W2,
                            ushort* __restrict__ W2T,
                            const float* __restrict__ W3,
                            ushort* __restrict__ W3T,
                            const int* __restrict__ dst, int* __restrict__ cnt,
                            int E) {
  int i = blockIdx.x * 256 + threadIdx.x;
  const int r0 = n_x4;
  const int r1 = r0 + 512 * 128;
  const int r2 = r1 + 64 * 512;
  const int r3 = r2 + 64 * 64;
  const int r4 = r3 + E;
  if (i < r0) {
    float4 v = x[i];
    uint2 o;
    o.x = (uint32_t)f2bf(v.x) | ((uint32_t)f2bf(v.y) << 16);
    o.y = (uint32_t)f2bf(v.z) | ((uint32_t)f2bf(v.w) << 16);
    x_bf[i] = o;
  } else if (i < r1) {
    int idx = i - r0;
    int n = idx >> 7, k = idx & 127;
    W1T[idx] = f2bf(W1[(size_t)k * 512 + n]);
  } else if (i < r2) {
    int idx = i - r1;
    int n = idx >> 9, k = idx & 511;
    W2T[idx] = f2bf(W2[(size_t)k * 64 + n]);
  } else if (i < r3) {
    int idx = i - r2;
    int n = idx >> 6, k = idx & 63;
    W3T[idx] = f2bf(W3[(size_t)k * 64 + n]);
  } else if (i < r4) {
    atomicAdd(&cnt[dst[i - r3]], 1);
  }
}

// ---------------------------------------------------------------------------
// GEMM1 + fused al: C[M,512] = A[M,128] @ W1 (BT=[512,128]).
// Block = 4 waves; wave = 16 rows x 128 cols (j=0..7). grid=(4, M/64).
// ---------------------------------------------------------------------------
__global__ __launch_bounds__(256) void gemm1_al(
    const ushort* __restrict__ A, const ushort* __restrict__ BT,
    ushort* __restrict__ C, const float* __restrict__ a1s,
    const float* __restrict__ a1d, float* __restrict__ al_s,
    float* __restrict__ al_d, int M) {
  const int K = 128;
  const int wave = threadIdx.x >> 6;
  const int lane = threadIdx.x & 63;
  const int rt = blockIdx.y * 4 + wave;
  const int r0 = rt * 16;
  if (r0 >= M) return;
  const int bx = blockIdx.x;
  const int n0 = bx * 128;
  const int l15 = lane & 15, q = lane >> 4;
  const ushort* Ap = A + (size_t)(r0 + l15) * K + q * 8;
  f32x4 acc[8] = {};
  for (int k0 = 0; k0 < K; k0 += 32) {
    bf16x8 a = *(const bf16x8*)(Ap + k0);
#pragma unroll
    for (int j = 0; j < 8; ++j) {
      const bf16x8 b =
          *(const bf16x8*)(BT + (size_t)(n0 + j * 16 + l15) * K + q * 8 + k0);
      acc[j] = __builtin_amdgcn_mfma_f32_16x16x32_bf16(a, b, acc[j], 0, 0, 0);
    }
  }
#pragma unroll
  for (int j = 0; j < 8; ++j)
#pragma unroll
    for (int r = 0; r < 4; ++r) {
      int row = r0 + q * 4 + r;
      C[(size_t)row * 512 + n0 + j * 16 + l15] = f2bf(acc[j][r]);
    }
  float als_p[2][4] = {{0.f}};
  float ald_p[2][4] = {{0.f}};
#pragma unroll
  for (int j = 0; j < 8; ++j) {
    int head = bx * 2 + (j >> 2);
    int cih = (j & 3) * 16 + l15;
    float wsc = a1s[head * 64 + cih];
    float wdc = a1d[head * 64 + cih];
#pragma unroll
    for (int r = 0; r < 4; ++r) {
      als_p[j >> 2][r] = fmaf(acc[j][r], wsc, als_p[j >> 2][r]);
      ald_p[j >> 2][r] = fmaf(acc[j][r], wdc, ald_p[j >> 2][r]);
    }
  }
#pragma unroll
  for (int g = 0; g < 2; ++g)
#pragma unroll
    for (int r = 0; r < 4; ++r) {
      float vs = als_p[g][r], vd = ald_p[g][r];
#pragma unroll
      for (int off = 1; off < 16; off <<= 1) {
        vs += __shfl_xor(vs, off);
        vd += __shfl_xor(vd, off);
      }
      if (l15 == 0) {
        int row = r0 + q * 4 + r;
        al_s[(size_t)row * 8 + bx * 2 + g] = vs;
        al_d[(size_t)row * 8 + bx * 2 + g] = vd;
      }
    }
}

// ---------------------------------------------------------------------------
// GEMM (N=64) + fused al (H=1): C[M,64] = A[M,K] @ BT[64,K].
// ---------------------------------------------------------------------------
__global__ __launch_bounds__(256) void gemm_n64_al(
    const ushort* __restrict__ A, const ushort* __restrict__ BT,
    ushort* __restrict__ C, const float* __restrict__ asrc,
    const float* __restrict__ adst, float* __restrict__ al_s,
    float* __restrict__ al_d, int M, int K) {
  const int wave = threadIdx.x >> 6;
  const int lane = threadIdx.x & 63;
  const int rt = blockIdx.y * 4 + wave;
  const int r0 = rt * 16;
  if (r0 >= M) return;
  const int l15 = lane & 15, q = lane >> 4;
  const ushort* Ap = A + (size_t)(r0 + l15) * K + q * 8;
  f32x4 acc[4] = {};
  for (int k0 = 0; k0 < K; k0 += 32) {
    bf16x8 a = *(const bf16x8*)(Ap + k0);
#pragma unroll
    for (int j = 0; j < 4; ++j) {
      const bf16x8 b =
          *(const bf16x8*)(BT + (size_t)(j * 16 + l15) * K + q * 8 + k0);
      acc[j] = __builtin_amdgcn_mfma_f32_16x16x32_bf16(a, b, acc[j], 0, 0, 0);
    }
  }
#pragma unroll
  for (int j = 0; j < 4; ++j)
#pragma unroll
    for (int r = 0; r < 4; ++r) {
      int row = r0 + q * 4 + r;
      C[(size_t)row * 64 + j * 16 + l15] = f2bf(acc[j][r]);
    }
  float als_p[4] = {0.f, 0.f, 0.f, 0.f};
  float ald_p[4] = {0.f, 0.f, 0.f, 0.f};
#pragma unroll
  for (int j = 0; j < 4; ++j) {
    float wsc = asrc[j * 16 + l15];
    float wdc = adst[j * 16 + l15];
#pragma unroll
    for (int r = 0; r < 4; ++r) {
      als_p[r] = fmaf(acc[j][r], wsc, als_p[r]);
      ald_p[r] = fmaf(acc[j][r], wdc, ald_p[r]);
    }
  }
#pragma unroll
  for (int r = 0; r < 4; ++r) {
    float vs = als_p[r], vd = ald_p[r];
#pragma unroll
    for (int off = 1; off < 16; off <<= 1) {
      vs += __shfl_xor(vs, off);
      vd += __shfl_xor(vd, off);
    }
    if (l15 == 0) {
      int row = r0 + q * 4 + r;
      al_s[row] = vs;
      al_d[row] = vd;
    }
  }
}

// ---------------------------------------------------------------------------
// CSR scan + scatter
// ---------------------------------------------------------------------------
__global__ void scan_block(const int* __restrict__ in, int* __restrict__ out,
                           int* __restrict__ bsum, int n) {
  __shared__ int sm[256];
  int gid = blockIdx.x * 256 + threadIdx.x;
  int v = (gid < n) ? in[gid] : 0;
  sm[threadIdx.x] = v;
  __syncthreads();
  for (int off = 1; off < 256; off <<= 1) {
    int t = (threadIdx.x >= off) ? sm[threadIdx.x - off] : 0;
    __syncthreads();
    sm[threadIdx.x] += t;
    __syncthreads();
  }
  if (gid < n) out[gid] = sm[threadIdx.x];
  if (threadIdx.x == 255) bsum[blockIdx.x] = sm[255];
}

__global__ void scan_bsum(int* __restrict__ bsum, int nb) {
  __shared__ int sm[256];
  int t = threadIdx.x;
  sm[t] = (t < nb) ? bsum[t] : 0;
  __syncthreads();
  for (int off = 1; off < 256; off <<= 1) {
    int v = (t >= off) ? sm[t - off] : 0;
    __syncthreads();
    sm[t] += v;
    __syncthreads();
  }
  if (t < nb) bsum[t] = sm[t];
}

__global__ void scan_final(const int* __restrict__ inc,
                           const int* __restrict__ bscan,
                           int* __restrict__ indptr, int n) {
  int gid = blockIdx.x * 256 + threadIdx.x;
  if (gid < n) {
    int add = blockIdx.x ? bscan[blockIdx.x - 1] : 0;
    indptr[gid + 1] = inc[gid] + add;
  }
  if (gid == 0) indptr[0] = 0;
}

__global__ void scatter_kernel(const int* __restrict__ src,
                               const int* __restrict__ dst,
                               const int* __restrict__ indptr,
                               int* __restrict__ fill,
                               int* __restrict__ csr_src, int E) {
  int e = blockIdx.x * 256 + threadIdx.x;
  if (e < E) {
    int dd = dst[e];
    int pos = indptr[dd] + atomicAdd(&fill[dd], 1);
    csr_src[pos] = src[e];
  }
}

// ---------------------------------------------------------------------------
// Attention layer 1: H=8, C=64, h1 bf16. ONE WAVE per dst node, no LDS,
// no barriers. Lane l accumulates channels l*8..l*8+7 (head l>>3).
// Alphas computed 8 edges x 8 heads per wave pass (lane j -> edge j>>3,
// head j&7), moved via __shfl. Unnormalized accumulate; no max subtraction
// (logits are O(1), exp is safe in fp32); divide by denom at the end.
// ---------------------------------------------------------------------------
__global__ __launch_bounds__(256) void attn1_kernel(
    const int* __restrict__ indptr, const int* __restrict__ csr_src,
    const float* __restrict__ al_s, const float* __restrict__ al_d,
    const ushort* __restrict__ h1, const float* __restrict__ b1,
    ushort* __restrict__ out1, int Nn) {
  const int w = (blockIdx.x * 256 + threadIdx.x) >> 6;
  const int l = threadIdx.x & 63;
  if (w >= Nn) return;
  const int d = w;
  const int start = indptr[d];
  const int deg = indptr[d + 1] - start;
  const int total = deg + 1;  // + self loop
  const int head = l >> 3;    // accumulation head for this lane
  const int hh = l & 7;       // compute-stage head for this lane
  const float ald_c = al_d[(size_t)d * 8 + hh];

  float acc[8] = {0.f, 0.f, 0.f, 0.f, 0.f, 0.f, 0.f, 0.f};
  float den = 0.f;
  const ushort* h1l = h1 + l * 8;

  for (int e0 = 0; e0 < total; e0 += 8) {
    // compute stage: lane j handles edge e0 + (j>>3), head j&7
    const int el = e0 + head;  // (l>>3) doubles as this lane's edge slot
    int s_j = d;
    float u = 0.f;
    if (el < total) {
      s_j = (el < deg) ? csr_src[start + el] : d;
      float v = al_s[(size_t)s_j * 8 + hh] + ald_c;
      v = fmaxf(v, NEG_SLOPE * v);
      u = __expf(v);
      den += u;
    }
    const int ne = min(8, total - e0);
    for (int e = 0; e < ne; ++e) {
      const float a = __shfl(u, e * 8 + head);
      const int s = __shfl(s_j, e * 8);
      const uint4 uu = *(const uint4*)(h1l + (size_t)s * 512);
      acc[0] = fmaf(a, lo16(uu.x), acc[0]);
      acc[1] = fmaf(a, hi16(uu.x), acc[1]);
      acc[2] = fmaf(a, lo16(uu.y), acc[2]);
      acc[3] = fmaf(a, hi16(uu.y), acc[3]);
      acc[4] = fmaf(a, lo16(uu.z), acc[4]);
      acc[5] = fmaf(a, hi16(uu.z), acc[5]);
      acc[6] = fmaf(a, lo16(uu.w), acc[6]);
      acc[7] = fmaf(a, hi16(uu.w), acc[7]);
    }
  }
  // reduce den over lanes with the same (l&7): xor 8,16,32 preserves l&7
  den += __shfl_xor(den, 8);
  den += __shfl_xor(den, 16);
  den += __shfl_xor(den, 32);
  // lane l now holds den for head l&7; fetch den for head (l>>3) from lane
  // (l>>3) (whose l&7 == l>>3).
  const float inv = 1.f / __shfl(den, head);

  const float4 bb0 = *(const float4*)(b1 + l * 8);
  const float4 bb1 = *(const float4*)(b1 + l * 8 + 4);
  float o[8];
  o[0] = acc[0] * inv + bb0.x;
  o[1] = acc[1] * inv + bb0.y;
  o[2] = acc[2] * inv + bb0.z;
  o[3] = acc[3] * inv + bb0.w;
  o[4] = acc[4] * inv + bb1.x;
  o[5] = acc[5] * inv + bb1.y;
  o[6] = acc[6] * inv + bb1.z;
  o[7] = acc[7] * inv + bb1.w;
#pragma unroll
  for (int k = 0; k < 8; ++k) o[k] = (o[k] > 0.f) ? o[k] : __expf(o[k]) - 1.f;
  uint4 st;
  st.x = (uint32_t)f2bf(o[0]) | ((uint32_t)f2bf(o[1]) << 16);
  st.y = (uint32_t)f2bf(o[2]) | ((uint32_t)f2bf(o[3]) << 16);
  st.z = (uint32_t)f2bf(o[4]) | ((uint32_t)f2bf(o[5]) << 16);
  st.w = (uint32_t)f2bf(o[6]) | ((uint32_t)f2bf(o[7]) << 16);
  *(uint4*)(out1 + (size_t)d * 512 + l * 8) = st;
}

// ---------------------------------------------------------------------------
// Attention layers 2/3: H=1, C=64, h bf16. One wave per node. Single pass:
// no max subtraction, unnormalized accumulate, divide at end.
// ---------------------------------------------------------------------------
__global__ __launch_bounds__(256) void attn_h1_kernel(
    const int* __restrict__ indptr, const int* __restrict__ csr_src,
    const float* __restrict__ al_s, const float* __restrict__ al_d,
    const ushort* __restrict__ hin, const float* __restrict__ bias,
    ushort* __restrict__ outp, int Nn) {
  int w = (blockIdx.x * 256 + threadIdx.x) >> 6;
  int lane = threadIdx.x & 63;
  if (w >= Nn) return;
  const int d = w;
  const int start = indptr[d];
  const int deg = indptr[d + 1] - start;
  const int total = deg + 1;
  const float ald = al_d[d];

  float acc = 0.f, den = 0.f;
  for (int e0 = 0; e0 < total; e0 += 64) {
    int e = e0 + lane;
    int s_j = d;
    float u = 0.f;
    if (e < total) {
      s_j = (e < deg) ? csr_src[start + e] : d;
      float v = al_s[s_j] + ald;
      v = fmaxf(v, NEG_SLOPE * v);
      u = __expf(v);
      den += u;
    }
    int ne = min(64, total - e0);
    for (int j = 0; j < ne; ++j) {
      float a = __shfl(u, j);
      int ss = __shfl(s_j, j);
      acc = fmaf(a, bf2f(hin[(size_t)ss * 64 + lane]), acc);
    }
  }
#pragma unroll
  for (int off = 32; off; off >>= 1) den += __shfl_xor(den, off);
  float v = acc / den + bias[lane];
  v = (v > 0.f) ? v : __expf(v) - 1.f;
  outp[(size_t)d * 64 + lane] = f2bf(v);
}

// ---------------------------------------------------------------------------
// Segmented global mean pool (sum part): batch is sorted, so accumulate runs
// locally and emit one atomic per (run, channel). Wave handles 64 nodes.
// ---------------------------------------------------------------------------
__global__ void pool_kernel(const ushort* __restrict__ out3,
                            const int* __restrict__ batch,
                            float* __restrict__ sums, int Nn) {
  int wave = (blockIdx.x * 256 + threadIdx.x) >> 6;
  int l = threadIdx.x & 63;
  int base = wave * 64;
  if (base >= Nn) return;
  int end = min(base + 64, Nn);
  float acc = 0.f;
  int cur = batch[base];
  for (int n = base; n < end; ++n) {
    int b = batch[n];
    if (b != cur) {
      atomicAdd(&sums[cur * 64 + l], acc);
      acc = 0.f;
      cur = b;
    }
    acc += bf2f(out3[(size_t)n * 64 + l]);
  }
  atomicAdd(&sums[cur * 64 + l], acc);
}

__global__ __launch_bounds__(256) void final_kernel(
    const float* __restrict__ sums, const int* __restrict__ batch, int Nn,
    const float* __restrict__ fcW, const float* __restrict__ fcb,
    float* __restrict__ out) {
  __shared__ int lb[65];
  __shared__ float inv_cnt[64];
  int tid = threadIdx.x;
  if (tid <= 64) {
    int lo = 0, hi = Nn;
    while (lo < hi) {
      int mid = (lo + hi) >> 1;
      if (batch[mid] < tid) lo = mid + 1; else hi = mid;
    }
    lb[tid] = lo;
  }
  __syncthreads();
  if (tid < 64) inv_cnt[tid] = 1.f / fmaxf((float)(lb[tid + 1] - lb[tid]), 1.f);
  __syncthreads();
  for (int i = tid; i < 64 * 10; i += 256) {
    int g = i / 10, o = i % 10;
    float acc = fcb[o];
    float inv = inv_cnt[g];
    for (int c = 0; c < 64; ++c)
      acc = fmaf(sums[g * 64 + c] * inv, fcW[c * 10 + o], acc);
    out[i] = acc;
  }
}

// ---------------------------------------------------------------------------
extern "C" void kernel_launch(void* const* d_in, const int* in_sizes, int n_in,
                              void* d_out, int out_size, void* d_ws,
                              size_t ws_size, hipStream_t stream) {
  const float* x = (const float*)d_in[0];
  const int* ei = (const int*)d_in[1];
  const int* batch = (const int*)d_in[2];
  const float* W1 = (const float*)d_in[3];
  const float* a1s = (const float*)d_in[4];
  const float* a1d = (const float*)d_in[5];
  const float* b1 = (const float*)d_in[6];
  const float* W2 = (const float*)d_in[7];
  const float* a2s = (const float*)d_in[8];
  const float* a2d = (const float*)d_in[9];
  const float* b2 = (const float*)d_in[10];
  const float* W3 = (const float*)d_in[11];
  const float* a3s = (const float*)d_in[12];
  const float* a3d = (const float*)d_in[13];
  const float* b3 = (const float*)d_in[14];
  const float* fcW = (const float*)d_in[15];
  const float* fcb = (const float*)d_in[16];
  float* out = (float*)d_out;

  const int N = in_sizes[0] / 128;  // 50000
  const int E = in_sizes[1] / 2;    // 800000
  const int* srcp = ei;
  const int* dstp = ei + E;

  // --- workspace layout ---
  char* ws = (char*)d_ws;
  size_t off = 0;
  auto alloc = [&](size_t bytes) -> void* {
    off = (off + 255) & ~(size_t)255;
    void* p = ws + off;
    off += bytes;
    return p;
  };
  ushort* x_bf = (ushort*)alloc((size_t)N * 128 * 2);
  ushort* W1T = (ushort*)alloc(512 * 128 * 2);
  ushort* W2T = (ushort*)alloc(64 * 512 * 2);
  ushort* W3T = (ushort*)alloc(64 * 64 * 2);
  ushort* h1 = (ushort*)alloc((size_t)N * 512 * 2);  // reused: h2/out2/h3/out3
  ushort* out1 = (ushort*)alloc((size_t)N * 512 * 2);
  float* al_s1 = (float*)alloc((size_t)N * 8 * 4);
  float* al_d1 = (float*)alloc((size_t)N * 8 * 4);
  float* al_s2 = (float*)alloc((size_t)N * 4);
  float* al_d2 = (float*)alloc((size_t)N * 4);
  float* al_s3 = (float*)alloc((size_t)N * 4);
  float* al_d3 = (float*)alloc((size_t)N * 4);
  int* cnt = (int*)alloc((size_t)N * 4);
  int* fill = (int*)alloc((size_t)N * 4);
  int* indptr = (int*)alloc((size_t)(N + 1) * 4);
  int* csr = (int*)alloc((size_t)E * 4);
  int* incbuf = (int*)alloc((size_t)N * 4);
  int* bsum = (int*)alloc(1024 * 4);
  float* sums = (float*)alloc(64 * 64 * 4);

  // aliases into the (dead-after-attn1) h1 region
  ushort* h2 = h1;
  ushort* out2 = h1 + (size_t)N * 64;
  ushort* h3 = h1 + (size_t)2 * N * 64;
  ushort* out3 = h1 + (size_t)3 * N * 64;

  hipMemsetAsync(cnt, 0, (size_t)N * 4, stream);
  hipMemsetAsync(fill, 0, (size_t)N * 4, stream);
  hipMemsetAsync(sums, 0, 64 * 64 * 4, stream);

  const int scan_blocks = (N + 255) / 256;
  const int row_blocks = (N / 16 + 3) / 4;

  // prep: x cast + weight transposes + CSR count
  const int n_x4 = N * 128 / 4;
  const int prep_total = n_x4 + 512 * 128 + 64 * 512 + 64 * 64 + E;
  prep_kernel<<<(prep_total + 255) / 256, 256, 0, stream>>>(
      (const float4*)x, (uint2*)x_bf, n_x4, W1, W1T, W2, W2T, W3, W3T, dstp,
      cnt, E);

  // GEMM1 + al1
  gemm1_al<<<dim3(4, row_blocks), 256, 0, stream>>>(x_bf, W1T, h1, a1s, a1d,
                                                    al_s1, al_d1, N);
  // CSR build
  scan_block<<<scan_blocks, 256, 0, stream>>>(cnt, incbuf, bsum, N);
  scan_bsum<<<1, 256, 0, stream>>>(bsum, scan_blocks);
  scan_final<<<scan_blocks, 256, 0, stream>>>(incbuf, bsum, indptr, N);
  scatter_kernel<<<(E + 255) / 256, 256, 0, stream>>>(srcp, dstp, indptr, fill,
                                                      csr, E);
  // Layer 1 attention + bias + ELU (wave per node)
  attn1_kernel<<<(N + 3) / 4, 256, 0, stream>>>(indptr, csr, al_s1, al_d1, h1,
                                                b1, out1, N);

  // Layer 2
  gemm_n64_al<<<dim3(1, row_blocks), 256, 0, stream>>>(out1, W2T, h2, a2s, a2d,
                                                       al_s2, al_d2, N, 512);
  attn_h1_kernel<<<(N + 3) / 4, 256, 0, stream>>>(indptr, csr, al_s2, al_d2, h2,
                                                  b2, out2, N);

  // Layer 3
  gemm_n64_al<<<dim3(1, row_blocks), 256, 0, stream>>>(out2, W3T, h3, a3s, a3d,
                                                       al_s3, al_d3, N, 64);
  attn_h1_kernel<<<(N + 3) / 4, 256, 0, stream>>>(indptr, csr, al_s3, al_d3, h3,
                                                  b3, out3, N);

  // Pool + FC
  pool_kernel<<<(N + 255) / 256 * 64 / 64, 256, 0, stream>>>(out3, batch, sums,
                                                             N);
  final_kernel<<<1, 256, 0, stream>>>(sums, batch, N, fcW, fcb, out);
}

// Round 5
// 547.867 us; speedup vs baseline: 1.9390x; 1.0771x over previous
//
#include <hip/hip_runtime.h>
#include <hip/hip_bf16.h>
#include <cstdint>

#define NEG_SLOPE 0.2f

typedef __attribute__((ext_vector_type(8))) short bf16x8;
typedef __attribute__((ext_vector_type(4))) float f32x4;

__device__ __forceinline__ float bf2f(uint32_t u) {
  union { float f; uint32_t i; } v;
  v.i = u << 16;
  return v.f;
}
__device__ __forceinline__ float lo16(uint32_t u) {
  union { float f; uint32_t i; } v;
  v.i = u << 16;
  return v.f;
}
__device__ __forceinline__ float hi16(uint32_t u) {
  union { float f; uint32_t i; } v;
  v.i = u & 0xffff0000u;
  return v.f;
}
__device__ __forceinline__ ushort f2bf(float f) {
  union { float f; uint32_t i; } v;
  v.f = f;
  uint32_t r = v.i + 0x7FFF + ((v.i >> 16) & 1);  // round-nearest-even
  return (ushort)(r >> 16);
}

// ---------------------------------------------------------------------------
// prep: cast x -> bf16 (vectorized), transpose+cast W1/W2/W3, CSR count pass.
// ---------------------------------------------------------------------------
__global__ void prep_kernel(const float4* __restrict__ x,
                            uint2* __restrict__ x_bf, int n_x4,
                            const float* __restrict__ W1,
                            ushort* __restrict__ W1T,
                            const float* __restrict__ W2,
                            ushort* __restrict__ W2T,
                            const float* __restrict__ W3,
                            ushort* __restrict__ W3T,
                            const int* __restrict__ dst, int* __restrict__ cnt,
                            int E) {
  int i = blockIdx.x * 256 + threadIdx.x;
  const int r0 = n_x4;
  const int r1 = r0 + 512 * 128;
  const int r2 = r1 + 64 * 512;
  const int r3 = r2 + 64 * 64;
  const int r4 = r3 + E;
  if (i < r0) {
    float4 v = x[i];
    uint2 o;
    o.x = (uint32_t)f2bf(v.x) | ((uint32_t)f2bf(v.y) << 16);
    o.y = (uint32_t)f2bf(v.z) | ((uint32_t)f2bf(v.w) << 16);
    x_bf[i] = o;
  } else if (i < r1) {
    int idx = i - r0;
    int n = idx >> 7, k = idx & 127;
    W1T[idx] = f2bf(W1[(size_t)k * 512 + n]);
  } else if (i < r2) {
    int idx = i - r1;
    int n = idx >> 9, k = idx & 511;
    W2T[idx] = f2bf(W2[(size_t)k * 64 + n]);
  } else if (i < r3) {
    int idx = i - r2;
    int n = idx >> 6, k = idx & 63;
    W3T[idx] = f2bf(W3[(size_t)k * 64 + n]);
  } else if (i < r4) {
    atomicAdd(&cnt[dst[i - r3]], 1);
  }
}

// ---------------------------------------------------------------------------
// GEMM1 + fused al: C[M,512] = A[M,128] @ W1 (BT=[512,128]).
// Block = 4 waves; wave = 16 rows x 128 cols (j=0..7). grid=(4, M/64).
// ---------------------------------------------------------------------------
__global__ __launch_bounds__(256) void gemm1_al(
    const ushort* __restrict__ A, const ushort* __restrict__ BT,
    ushort* __restrict__ C, const float* __restrict__ a1s,
    const float* __restrict__ a1d, float* __restrict__ al_s,
    float* __restrict__ al_d, int M) {
  const int K = 128;
  const int wave = threadIdx.x >> 6;
  const int lane = threadIdx.x & 63;
  const int rt = blockIdx.y * 4 + wave;
  const int r0 = rt * 16;
  if (r0 >= M) return;
  const int bx = blockIdx.x;
  const int n0 = bx * 128;
  const int l15 = lane & 15, q = lane >> 4;
  const ushort* Ap = A + (size_t)(r0 + l15) * K + q * 8;
  f32x4 acc[8] = {};
  for (int k0 = 0; k0 < K; k0 += 32) {
    bf16x8 a = *(const bf16x8*)(Ap + k0);
#pragma unroll
    for (int j = 0; j < 8; ++j) {
      const bf16x8 b =
          *(const bf16x8*)(BT + (size_t)(n0 + j * 16 + l15) * K + q * 8 + k0);
      acc[j] = __builtin_amdgcn_mfma_f32_16x16x32_bf16(a, b, acc[j], 0, 0, 0);
    }
  }
#pragma unroll
  for (int j = 0; j < 8; ++j)
#pragma unroll
    for (int r = 0; r < 4; ++r) {
      int row = r0 + q * 4 + r;
      C[(size_t)row * 512 + n0 + j * 16 + l15] = f2bf(acc[j][r]);
    }
  float als_p[2][4] = {{0.f}};
  float ald_p[2][4] = {{0.f}};
#pragma unroll
  for (int j = 0; j < 8; ++j) {
    int head = bx * 2 + (j >> 2);
    int cih = (j & 3) * 16 + l15;
    float wsc = a1s[head * 64 + cih];
    float wdc = a1d[head * 64 + cih];
#pragma unroll
    for (int r = 0; r < 4; ++r) {
      als_p[j >> 2][r] = fmaf(acc[j][r], wsc, als_p[j >> 2][r]);
      ald_p[j >> 2][r] = fmaf(acc[j][r], wdc, ald_p[j >> 2][r]);
    }
  }
#pragma unroll
  for (int g = 0; g < 2; ++g)
#pragma unroll
    for (int r = 0; r < 4; ++r) {
      float vs = als_p[g][r], vd = ald_p[g][r];
#pragma unroll
      for (int off = 1; off < 16; off <<= 1) {
        vs += __shfl_xor(vs, off);
        vd += __shfl_xor(vd, off);
      }
      if (l15 == 0) {
        int row = r0 + q * 4 + r;
        al_s[(size_t)row * 8 + bx * 2 + g] = vs;
        al_d[(size_t)row * 8 + bx * 2 + g] = vd;
      }
    }
}

// ---------------------------------------------------------------------------
// GEMM (N=64) + fused al (H=1): C[M,64] = A[M,K] @ BT[64,K].
// ---------------------------------------------------------------------------
__global__ __launch_bounds__(256) void gemm_n64_al(
    const ushort* __restrict__ A, const ushort* __restrict__ BT,
    ushort* __restrict__ C, const float* __restrict__ asrc,
    const float* __restrict__ adst, float* __restrict__ al_s,
    float* __restrict__ al_d, int M, int K) {
  const int wave = threadIdx.x >> 6;
  const int lane = threadIdx.x & 63;
  const int rt = blockIdx.y * 4 + wave;
  const int r0 = rt * 16;
  if (r0 >= M) return;
  const int l15 = lane & 15, q = lane >> 4;
  const ushort* Ap = A + (size_t)(r0 + l15) * K + q * 8;
  f32x4 acc[4] = {};
  for (int k0 = 0; k0 < K; k0 += 32) {
    bf16x8 a = *(const bf16x8*)(Ap + k0);
#pragma unroll
    for (int j = 0; j < 4; ++j) {
      const bf16x8 b =
          *(const bf16x8*)(BT + (size_t)(j * 16 + l15) * K + q * 8 + k0);
      acc[j] = __builtin_amdgcn_mfma_f32_16x16x32_bf16(a, b, acc[j], 0, 0, 0);
    }
  }
#pragma unroll
  for (int j = 0; j < 4; ++j)
#pragma unroll
    for (int r = 0; r < 4; ++r) {
      int row = r0 + q * 4 + r;
      C[(size_t)row * 64 + j * 16 + l15] = f2bf(acc[j][r]);
    }
  float als_p[4] = {0.f, 0.f, 0.f, 0.f};
  float ald_p[4] = {0.f, 0.f, 0.f, 0.f};
#pragma unroll
  for (int j = 0; j < 4; ++j) {
    float wsc = asrc[j * 16 + l15];
    float wdc = adst[j * 16 + l15];
#pragma unroll
    for (int r = 0; r < 4; ++r) {
      als_p[r] = fmaf(acc[j][r], wsc, als_p[r]);
      ald_p[r] = fmaf(acc[j][r], wdc, ald_p[r]);
    }
  }
#pragma unroll
  for (int r = 0; r < 4; ++r) {
    float vs = als_p[r], vd = ald_p[r];
#pragma unroll
    for (int off = 1; off < 16; off <<= 1) {
      vs += __shfl_xor(vs, off);
      vd += __shfl_xor(vd, off);
    }
    if (l15 == 0) {
      int row = r0 + q * 4 + r;
      al_s[row] = vs;
      al_d[row] = vd;
    }
  }
}

// ---------------------------------------------------------------------------
// CSR: per-block inclusive scan (block sums to bsum)
// ---------------------------------------------------------------------------
__global__ void scan_block(const int* __restrict__ in, int* __restrict__ out,
                           int* __restrict__ bsum, int n) {
  __shared__ int sm[256];
  int gid = blockIdx.x * 256 + threadIdx.x;
  int v = (gid < n) ? in[gid] : 0;
  sm[threadIdx.x] = v;
  __syncthreads();
  for (int off = 1; off < 256; off <<= 1) {
    int t = (threadIdx.x >= off) ? sm[threadIdx.x - off] : 0;
    __syncthreads();
    sm[threadIdx.x] += t;
    __syncthreads();
  }
  if (gid < n) out[gid] = sm[threadIdx.x];
  if (threadIdx.x == 255) bsum[blockIdx.x] = sm[255];
}

// Each block redundantly reduces the <=256 block sums below it, then emits
// indptr AND fill(=indptr copy) so scatter needs no memset and no indptr read.
__global__ void scan_final2(const int* __restrict__ inc,
                            const int* __restrict__ bsum,
                            int* __restrict__ indptr, int* __restrict__ fill,
                            int n) {
  __shared__ int sm[256];
  const int t = threadIdx.x, bx = blockIdx.x;
  sm[t] = (t < bx) ? bsum[t] : 0;  // gridDim <= 256 (N <= 65536)
  __syncthreads();
  for (int off = 128; off; off >>= 1) {
    if (t < off) sm[t] += sm[t + off];
    __syncthreads();
  }
  const int prefix = sm[0];
  int gid = bx * 256 + t;
  if (gid < n) {
    int val = inc[gid] + prefix;
    indptr[gid + 1] = val;
    fill[gid + 1] = val;
  }
  if (gid == 0) {
    indptr[0] = 0;
    fill[0] = 0;
  }
}

__global__ void scatter_kernel(const int* __restrict__ src,
                               const int* __restrict__ dst,
                               int* __restrict__ fill,
                               int* __restrict__ csr_src, int E) {
  int e = blockIdx.x * 256 + threadIdx.x;
  if (e < E) {
    int pos = atomicAdd(&fill[dst[e]], 1);
    csr_src[pos] = src[e];
  }
}

// ---------------------------------------------------------------------------
// Attention layer 1: H=8, C=64, h1 bf16. ONE WAVE per dst node, no LDS.
// Lane l accumulates channels l*8..l*8+7 (head l>>3). Alphas: lane j ->
// edge j>>3, head j&7, moved via __shfl. Inner loop is a FIXED unrolled 8
// (invalid slots carry u=0, s=d) so 8 dwordx4 loads are in flight.
// ---------------------------------------------------------------------------
__global__ __launch_bounds__(256) void attn1_kernel(
    const int* __restrict__ indptr, const int* __restrict__ csr_src,
    const float* __restrict__ al_s, const float* __restrict__ al_d,
    const ushort* __restrict__ h1, const float* __restrict__ b1,
    ushort* __restrict__ out1, int Nn) {
  const int w = (blockIdx.x * 256 + threadIdx.x) >> 6;
  const int l = threadIdx.x & 63;
  if (w >= Nn) return;
  const int d = w;
  const int start = indptr[d];
  const int deg = indptr[d + 1] - start;
  const int total = deg + 1;  // + self loop
  const int head = l >> 3;    // accumulation head / edge slot for this lane
  const int hh = l & 7;       // compute-stage head for this lane
  const float ald_c = al_d[(size_t)d * 8 + hh];

  float acc[8] = {0.f, 0.f, 0.f, 0.f, 0.f, 0.f, 0.f, 0.f};
  float den = 0.f;
  const ushort* h1l = h1 + l * 8;

  for (int e0 = 0; e0 < total; e0 += 8) {
    // compute stage: lane j handles edge e0 + (j>>3), head j&7
    const int el = e0 + head;
    int s_j = d;
    float u = 0.f;
    if (el < total) {
      s_j = (el < deg) ? csr_src[start + el] : d;
      float v = al_s[(size_t)s_j * 8 + hh] + ald_c;
      v = fmaxf(v, NEG_SLOPE * v);
      u = __expf(v);
      den += u;
    }
#pragma unroll
    for (int e = 0; e < 8; ++e) {
      const float a = __shfl(u, e * 8 + head);
      const int s = __shfl(s_j, e * 8);
      const uint4 uu = *(const uint4*)(h1l + (size_t)s * 512);
      acc[0] = fmaf(a, lo16(uu.x), acc[0]);
      acc[1] = fmaf(a, hi16(uu.x), acc[1]);
      acc[2] = fmaf(a, lo16(uu.y), acc[2]);
      acc[3] = fmaf(a, hi16(uu.y), acc[3]);
      acc[4] = fmaf(a, lo16(uu.z), acc[4]);
      acc[5] = fmaf(a, hi16(uu.z), acc[5]);
      acc[6] = fmaf(a, lo16(uu.w), acc[6]);
      acc[7] = fmaf(a, hi16(uu.w), acc[7]);
    }
  }
  // reduce den over lanes with same (l&7): xor 8,16,32 preserves l&7
  den += __shfl_xor(den, 8);
  den += __shfl_xor(den, 16);
  den += __shfl_xor(den, 32);
  const float inv = 1.f / __shfl(den, head);

  const float4 bb0 = *(const float4*)(b1 + l * 8);
  const float4 bb1 = *(const float4*)(b1 + l * 8 + 4);
  float o[8];
  o[0] = acc[0] * inv + bb0.x;
  o[1] = acc[1] * inv + bb0.y;
  o[2] = acc[2] * inv + bb0.z;
  o[3] = acc[3] * inv + bb0.w;
  o[4] = acc[4] * inv + bb1.x;
  o[5] = acc[5] * inv + bb1.y;
  o[6] = acc[6] * inv + bb1.z;
  o[7] = acc[7] * inv + bb1.w;
#pragma unroll
  for (int k = 0; k < 8; ++k) o[k] = (o[k] > 0.f) ? o[k] : __expf(o[k]) - 1.f;
  uint4 st;
  st.x = (uint32_t)f2bf(o[0]) | ((uint32_t)f2bf(o[1]) << 16);
  st.y = (uint32_t)f2bf(o[2]) | ((uint32_t)f2bf(o[3]) << 16);
  st.z = (uint32_t)f2bf(o[4]) | ((uint32_t)f2bf(o[5]) << 16);
  st.w = (uint32_t)f2bf(o[6]) | ((uint32_t)f2bf(o[7]) << 16);
  *(uint4*)(out1 + (size_t)d * 512 + l * 8) = st;
}

// ---------------------------------------------------------------------------
// Attention layers 2/3: H=1, C=64, h bf16. One wave per node. Single pass,
// inner loop in unrolled groups of 8 (dummy slots carry a=0, s=d).
// ---------------------------------------------------------------------------
__global__ __launch_bounds__(256) void attn_h1_kernel(
    const int* __restrict__ indptr, const int* __restrict__ csr_src,
    const float* __restrict__ al_s, const float* __restrict__ al_d,
    const ushort* __restrict__ hin, const float* __restrict__ bias,
    ushort* __restrict__ outp, int Nn) {
  int w = (blockIdx.x * 256 + threadIdx.x) >> 6;
  int lane = threadIdx.x & 63;
  if (w >= Nn) return;
  const int d = w;
  const int start = indptr[d];
  const int deg = indptr[d + 1] - start;
  const int total = deg + 1;
  const float ald = al_d[d];

  float acc = 0.f, den = 0.f;
  for (int e0 = 0; e0 < total; e0 += 64) {
    int e = e0 + lane;
    int s_j = d;
    float u = 0.f;
    if (e < total) {
      s_j = (e < deg) ? csr_src[start + e] : d;
      float v = al_s[s_j] + ald;
      v = fmaxf(v, NEG_SLOPE * v);
      u = __expf(v);
      den += u;
    }
    int ne = min(64, total - e0);
    for (int j = 0; j < ne; j += 8) {
      float av[8];
      int sv[8];
#pragma unroll
      for (int k = 0; k < 8; ++k) {
        av[k] = __shfl(u, j + k);
        sv[k] = __shfl(s_j, j + k);
      }
      float hv[8];
#pragma unroll
      for (int k = 0; k < 8; ++k)
        hv[k] = bf2f(hin[(size_t)sv[k] * 64 + lane]);
#pragma unroll
      for (int k = 0; k < 8; ++k) acc = fmaf(av[k], hv[k], acc);
    }
  }
#pragma unroll
  for (int off = 32; off; off >>= 1) den += __shfl_xor(den, off);
  float v = acc / den + bias[lane];
  v = (v > 0.f) ? v : __expf(v) - 1.f;
  outp[(size_t)d * 64 + lane] = f2bf(v);
}

// ---------------------------------------------------------------------------
// Fused global mean pool + FC. One block per graph (batch sorted ->
// binary-search bounds). No atomics, no sums buffer.
// ---------------------------------------------------------------------------
__global__ __launch_bounds__(256) void poolfc_kernel(
    const ushort* __restrict__ out3, const int* __restrict__ batch, int Nn,
    const float* __restrict__ fcW, const float* __restrict__ fcb,
    float* __restrict__ out) {
  const int g = blockIdx.x;
  const int t = threadIdx.x;
  __shared__ float red[4][64];
  __shared__ float pooled[64];
  __shared__ int bounds[2];
  if (t < 2) {
    int target = g + t;
    int lo = 0, hi = Nn;
    while (lo < hi) {
      int mid = (lo + hi) >> 1;
      if (batch[mid] < target) lo = mid + 1; else hi = mid;
    }
    bounds[t] = lo;
  }
  __syncthreads();
  const int lb = bounds[0], ub = bounds[1];
  const int c = t & 63, r = t >> 6;
  float acc = 0.f;
  for (int n = lb + r; n < ub; n += 4)
    acc += bf2f(out3[(size_t)n * 64 + c]);
  red[r][c] = acc;
  __syncthreads();
  if (t < 64) {
    float s = red[0][t] + red[1][t] + red[2][t] + red[3][t];
    pooled[t] = s / fmaxf((float)(ub - lb), 1.f);
  }
  __syncthreads();
  if (t < 10) {
    float a = fcb[t];
    for (int cc = 0; cc < 64; ++cc) a = fmaf(pooled[cc], fcW[cc * 10 + t], a);
    out[g * 10 + t] = a;
  }
}

// ---------------------------------------------------------------------------
extern "C" void kernel_launch(void* const* d_in, const int* in_sizes, int n_in,
                              void* d_out, int out_size, void* d_ws,
                              size_t ws_size, hipStream_t stream) {
  const float* x = (const float*)d_in[0];
  const int* ei = (const int*)d_in[1];
  const int* batch = (const int*)d_in[2];
  const float* W1 = (const float*)d_in[3];
  const float* a1s = (const float*)d_in[4];
  const float* a1d = (const float*)d_in[5];
  const float* b1 = (const float*)d_in[6];
  const float* W2 = (const float*)d_in[7];
  const float* a2s = (const float*)d_in[8];
  const float* a2d = (const float*)d_in[9];
  const float* b2 = (const float*)d_in[10];
  const float* W3 = (const float*)d_in[11];
  const float* a3s = (const float*)d_in[12];
  const float* a3d = (const float*)d_in[13];
  const float* b3 = (const float*)d_in[14];
  const float* fcW = (const float*)d_in[15];
  const float* fcb = (const float*)d_in[16];
  float* out = (float*)d_out;

  const int N = in_sizes[0] / 128;  // 50000
  const int E = in_sizes[1] / 2;    // 800000
  const int* srcp = ei;
  const int* dstp = ei + E;

  // --- workspace layout ---
  char* ws = (char*)d_ws;
  size_t off = 0;
  auto alloc = [&](size_t bytes) -> void* {
    off = (off + 255) & ~(size_t)255;
    void* p = ws + off;
    off += bytes;
    return p;
  };
  ushort* x_bf = (ushort*)alloc((size_t)N * 128 * 2);
  ushort* W1T = (ushort*)alloc(512 * 128 * 2);
  ushort* W2T = (ushort*)alloc(64 * 512 * 2);
  ushort* W3T = (ushort*)alloc(64 * 64 * 2);
  ushort* h1 = (ushort*)alloc((size_t)N * 512 * 2);  // reused: h2/out2/h3/out3
  ushort* out1 = (ushort*)alloc((size_t)N * 512 * 2);
  float* al_s1 = (float*)alloc((size_t)N * 8 * 4);
  float* al_d1 = (float*)alloc((size_t)N * 8 * 4);
  float* al_s2 = (float*)alloc((size_t)N * 4);
  float* al_d2 = (float*)alloc((size_t)N * 4);
  float* al_s3 = (float*)alloc((size_t)N * 4);
  float* al_d3 = (float*)alloc((size_t)N * 4);
  int* cnt = (int*)alloc((size_t)N * 4);
  int* fill = (int*)alloc((size_t)(N + 1) * 4);
  int* indptr = (int*)alloc((size_t)(N + 1) * 4);
  int* csr = (int*)alloc((size_t)E * 4);
  int* incbuf = (int*)alloc((size_t)N * 4);
  int* bsum = (int*)alloc(1024 * 4);

  // aliases into the (dead-after-attn1) h1 region
  ushort* h2 = h1;
  ushort* out2 = h1 + (size_t)N * 64;
  ushort* h3 = h1 + (size_t)2 * N * 64;
  ushort* out3 = h1 + (size_t)3 * N * 64;

  hipMemsetAsync(cnt, 0, (size_t)N * 4, stream);

  const int scan_blocks = (N + 255) / 256;  // 196 (<256 required)
  const int row_blocks = (N / 16 + 3) / 4;

  // prep: x cast + weight transposes + CSR count
  const int n_x4 = N * 128 / 4;
  const int prep_total = n_x4 + 512 * 128 + 64 * 512 + 64 * 64 + E;
  prep_kernel<<<(prep_total + 255) / 256, 256, 0, stream>>>(
      (const float4*)x, (uint2*)x_bf, n_x4, W1, W1T, W2, W2T, W3, W3T, dstp,
      cnt, E);

  // GEMM1 + al1
  gemm1_al<<<dim3(4, row_blocks), 256, 0, stream>>>(x_bf, W1T, h1, a1s, a1d,
                                                    al_s1, al_d1, N);
  // CSR build
  scan_block<<<scan_blocks, 256, 0, stream>>>(cnt, incbuf, bsum, N);
  scan_final2<<<scan_blocks, 256, 0, stream>>>(incbuf, bsum, indptr, fill, N);
  scatter_kernel<<<(E + 255) / 256, 256, 0, stream>>>(srcp, dstp, fill, csr, E);
  // Layer 1 attention + bias + ELU (wave per node)
  attn1_kernel<<<(N + 3) / 4, 256, 0, stream>>>(indptr, csr, al_s1, al_d1, h1,
                                                b1, out1, N);

  // Layer 2
  gemm_n64_al<<<dim3(1, row_blocks), 256, 0, stream>>>(out1, W2T, h2, a2s, a2d,
                                                       al_s2, al_d2, N, 512);
  attn_h1_kernel<<<(N + 3) / 4, 256, 0, stream>>>(indptr, csr, al_s2, al_d2, h2,
                                                  b2, out2, N);

  // Layer 3
  gemm_n64_al<<<dim3(1, row_blocks), 256, 0, stream>>>(out2, W3T, h3, a3s, a3d,
                                                       al_s3, al_d3, N, 64);
  attn_h1_kernel<<<(N + 3) / 4, 256, 0, stream>>>(indptr, csr, al_s3, al_d3, h3,
                                                  b3, out3, N);

  // Fused pool + FC
  poolfc_kernel<<<64, 256, 0, stream>>>(out3, batch, N, fcW, fcb, out);
}

// Round 6
// 542.796 us; speedup vs baseline: 1.9571x; 1.0093x over previous
//
#include <hip/hip_runtime.h>
#include <hip/hip_bf16.h>
#include <cstdint>

#define NEG_SLOPE 0.2f

typedef __attribute__((ext_vector_type(8))) short bf16x8;
typedef __attribute__((ext_vector_type(4))) float f32x4;

__device__ __forceinline__ float bf2f(uint32_t u) {
  union { float f; uint32_t i; } v;
  v.i = u << 16;
  return v.f;
}
__device__ __forceinline__ float lo16(uint32_t u) {
  union { float f; uint32_t i; } v;
  v.i = u << 16;
  return v.f;
}
__device__ __forceinline__ float hi16(uint32_t u) {
  union { float f; uint32_t i; } v;
  v.i = u & 0xffff0000u;
  return v.f;
}
__device__ __forceinline__ ushort f2bf(float f) {
  union { float f; uint32_t i; } v;
  v.f = f;
  uint32_t r = v.i + 0x7FFF + ((v.i >> 16) & 1);  // round-nearest-even
  return (ushort)(r >> 16);
}

// ---------------------------------------------------------------------------
// prep: cast x -> bf16, transpose+cast W1/W2/W3, CSR count pass, zero sums.
// ---------------------------------------------------------------------------
__global__ void prep_kernel(const float4* __restrict__ x,
                            uint2* __restrict__ x_bf, int n_x4,
                            const float* __restrict__ W1,
                            ushort* __restrict__ W1T,
                            const float* __restrict__ W2,
                            ushort* __restrict__ W2T,
                            const float* __restrict__ W3,
                            ushort* __restrict__ W3T,
                            const int* __restrict__ dst, int* __restrict__ cnt,
                            float* __restrict__ sums, int E) {
  int i = blockIdx.x * 256 + threadIdx.x;
  const int r0 = n_x4;
  const int r1 = r0 + 512 * 128;
  const int r2 = r1 + 64 * 512;
  const int r3 = r2 + 64 * 64;
  const int r4 = r3 + E;
  const int r5 = r4 + 64 * 64;
  if (i < r0) {
    float4 v = x[i];
    uint2 o;
    o.x = (uint32_t)f2bf(v.x) | ((uint32_t)f2bf(v.y) << 16);
    o.y = (uint32_t)f2bf(v.z) | ((uint32_t)f2bf(v.w) << 16);
    x_bf[i] = o;
  } else if (i < r1) {
    int idx = i - r0;
    int n = idx >> 7, k = idx & 127;
    W1T[idx] = f2bf(W1[(size_t)k * 512 + n]);
  } else if (i < r2) {
    int idx = i - r1;
    int n = idx >> 9, k = idx & 511;
    W2T[idx] = f2bf(W2[(size_t)k * 64 + n]);
  } else if (i < r3) {
    int idx = i - r2;
    int n = idx >> 6, k = idx & 63;
    W3T[idx] = f2bf(W3[(size_t)k * 64 + n]);
  } else if (i < r4) {
    atomicAdd(&cnt[dst[i - r3]], 1);
  } else if (i < r5) {
    sums[i - r4] = 0.f;
  }
}

// ---------------------------------------------------------------------------
// GEMM1 + fused al: C[M,512] = A[M,128] @ W1 (BT=[512,128]).
// ---------------------------------------------------------------------------
__global__ __launch_bounds__(256) void gemm1_al(
    const ushort* __restrict__ A, const ushort* __restrict__ BT,
    ushort* __restrict__ C, const float* __restrict__ a1s,
    const float* __restrict__ a1d, float* __restrict__ al_s,
    float* __restrict__ al_d, int M) {
  const int K = 128;
  const int wave = threadIdx.x >> 6;
  const int lane = threadIdx.x & 63;
  const int rt = blockIdx.y * 4 + wave;
  const int r0 = rt * 16;
  if (r0 >= M) return;
  const int bx = blockIdx.x;
  const int n0 = bx * 128;
  const int l15 = lane & 15, q = lane >> 4;
  const ushort* Ap = A + (size_t)(r0 + l15) * K + q * 8;
  f32x4 acc[8] = {};
  for (int k0 = 0; k0 < K; k0 += 32) {
    bf16x8 a = *(const bf16x8*)(Ap + k0);
#pragma unroll
    for (int j = 0; j < 8; ++j) {
      const bf16x8 b =
          *(const bf16x8*)(BT + (size_t)(n0 + j * 16 + l15) * K + q * 8 + k0);
      acc[j] = __builtin_amdgcn_mfma_f32_16x16x32_bf16(a, b, acc[j], 0, 0, 0);
    }
  }
#pragma unroll
  for (int j = 0; j < 8; ++j)
#pragma unroll
    for (int r = 0; r < 4; ++r) {
      int row = r0 + q * 4 + r;
      C[(size_t)row * 512 + n0 + j * 16 + l15] = f2bf(acc[j][r]);
    }
  float als_p[2][4] = {{0.f}};
  float ald_p[2][4] = {{0.f}};
#pragma unroll
  for (int j = 0; j < 8; ++j) {
    int head = bx * 2 + (j >> 2);
    int cih = (j & 3) * 16 + l15;
    float wsc = a1s[head * 64 + cih];
    float wdc = a1d[head * 64 + cih];
#pragma unroll
    for (int r = 0; r < 4; ++r) {
      als_p[j >> 2][r] = fmaf(acc[j][r], wsc, als_p[j >> 2][r]);
      ald_p[j >> 2][r] = fmaf(acc[j][r], wdc, ald_p[j >> 2][r]);
    }
  }
#pragma unroll
  for (int g = 0; g < 2; ++g)
#pragma unroll
    for (int r = 0; r < 4; ++r) {
      float vs = als_p[g][r], vd = ald_p[g][r];
#pragma unroll
      for (int off = 1; off < 16; off <<= 1) {
        vs += __shfl_xor(vs, off);
        vd += __shfl_xor(vd, off);
      }
      if (l15 == 0) {
        int row = r0 + q * 4 + r;
        al_s[(size_t)row * 8 + bx * 2 + g] = vs;
        al_d[(size_t)row * 8 + bx * 2 + g] = vd;
      }
    }
}

// ---------------------------------------------------------------------------
// GEMM (N=64) + fused al (H=1): C[M,64] = A[M,K] @ BT[64,K].
// ---------------------------------------------------------------------------
__global__ __launch_bounds__(256) void gemm_n64_al(
    const ushort* __restrict__ A, const ushort* __restrict__ BT,
    ushort* __restrict__ C, const float* __restrict__ asrc,
    const float* __restrict__ adst, float* __restrict__ al_s,
    float* __restrict__ al_d, int M, int K) {
  const int wave = threadIdx.x >> 6;
  const int lane = threadIdx.x & 63;
  const int rt = blockIdx.y * 4 + wave;
  const int r0 = rt * 16;
  if (r0 >= M) return;
  const int l15 = lane & 15, q = lane >> 4;
  const ushort* Ap = A + (size_t)(r0 + l15) * K + q * 8;
  f32x4 acc[4] = {};
  for (int k0 = 0; k0 < K; k0 += 32) {
    bf16x8 a = *(const bf16x8*)(Ap + k0);
#pragma unroll
    for (int j = 0; j < 4; ++j) {
      const bf16x8 b =
          *(const bf16x8*)(BT + (size_t)(j * 16 + l15) * K + q * 8 + k0);
      acc[j] = __builtin_amdgcn_mfma_f32_16x16x32_bf16(a, b, acc[j], 0, 0, 0);
    }
  }
#pragma unroll
  for (int j = 0; j < 4; ++j)
#pragma unroll
    for (int r = 0; r < 4; ++r) {
      int row = r0 + q * 4 + r;
      C[(size_t)row * 64 + j * 16 + l15] = f2bf(acc[j][r]);
    }
  float als_p[4] = {0.f, 0.f, 0.f, 0.f};
  float ald_p[4] = {0.f, 0.f, 0.f, 0.f};
#pragma unroll
  for (int j = 0; j < 4; ++j) {
    float wsc = asrc[j * 16 + l15];
    float wdc = adst[j * 16 + l15];
#pragma unroll
    for (int r = 0; r < 4; ++r) {
      als_p[r] = fmaf(acc[j][r], wsc, als_p[r]);
      ald_p[r] = fmaf(acc[j][r], wdc, ald_p[r]);
    }
  }
#pragma unroll
  for (int r = 0; r < 4; ++r) {
    float vs = als_p[r], vd = ald_p[r];
#pragma unroll
    for (int off = 1; off < 16; off <<= 1) {
      vs += __shfl_xor(vs, off);
      vd += __shfl_xor(vd, off);
    }
    if (l15 == 0) {
      int row = r0 + q * 4 + r;
      al_s[row] = vs;
      al_d[row] = vd;
    }
  }
}

// ---------------------------------------------------------------------------
// CSR: per-block inclusive scan (block sums to bsum)
// ---------------------------------------------------------------------------
__global__ void scan_block(const int* __restrict__ in, int* __restrict__ out,
                           int* __restrict__ bsum, int n) {
  __shared__ int sm[256];
  int gid = blockIdx.x * 256 + threadIdx.x;
  int v = (gid < n) ? in[gid] : 0;
  sm[threadIdx.x] = v;
  __syncthreads();
  for (int off = 1; off < 256; off <<= 1) {
    int t = (threadIdx.x >= off) ? sm[threadIdx.x - off] : 0;
    __syncthreads();
    sm[threadIdx.x] += t;
    __syncthreads();
  }
  if (gid < n) out[gid] = sm[threadIdx.x];
  if (threadIdx.x == 255) bsum[blockIdx.x] = sm[255];
}

__global__ void scan_final2(const int* __restrict__ inc,
                            const int* __restrict__ bsum,
                            int* __restrict__ indptr, int* __restrict__ fill,
                            int n) {
  __shared__ int sm[256];
  const int t = threadIdx.x, bx = blockIdx.x;
  sm[t] = (t < bx) ? bsum[t] : 0;  // gridDim <= 256
  __syncthreads();
  for (int off = 128; off; off >>= 1) {
    if (t < off) sm[t] += sm[t + off];
    __syncthreads();
  }
  const int prefix = sm[0];
  int gid = bx * 256 + t;
  if (gid < n) {
    int val = inc[gid] + prefix;
    indptr[gid + 1] = val;
    fill[gid + 1] = val;
  }
  if (gid == 0) {
    indptr[0] = 0;
    fill[0] = 0;
  }
}

__global__ void scatter_kernel(const int* __restrict__ src,
                               const int* __restrict__ dst,
                               int* __restrict__ fill,
                               int* __restrict__ csr_src, int E) {
  int e = blockIdx.x * 256 + threadIdx.x;
  if (e < E) {
    int pos = atomicAdd(&fill[dst[e]], 1);
    csr_src[pos] = src[e];
  }
}

// ---------------------------------------------------------------------------
// Attention layer 1: H=8, C=64, h1 bf16. ONE WAVE per dst node, no LDS.
// Software-pipelined: csr_src + al_s for group g+1 prefetched while group g's
// row loads + fmas run, hiding the two dependent gather latencies.
// ---------------------------------------------------------------------------
__global__ __launch_bounds__(256) void attn1_kernel(
    const int* __restrict__ indptr, const int* __restrict__ csr_src,
    const float* __restrict__ al_s, const float* __restrict__ al_d,
    const ushort* __restrict__ h1, const float* __restrict__ b1,
    ushort* __restrict__ out1, int Nn) {
  const int w = (blockIdx.x * 256 + threadIdx.x) >> 6;
  const int l = threadIdx.x & 63;
  if (w >= Nn) return;
  const int d = w;
  const int start = indptr[d];
  const int deg = indptr[d + 1] - start;
  const int total = deg + 1;  // + self loop
  const int head = l >> 3;    // accumulation head / edge slot for this lane
  const int hh = l & 7;       // compute-stage head for this lane
  const float ald_c = al_d[(size_t)d * 8 + hh];

  float acc[8] = {0.f, 0.f, 0.f, 0.f, 0.f, 0.f, 0.f, 0.f};
  float den = 0.f;
  const ushort* h1l = h1 + l * 8;

  // prologue: prefetch group 0
  int s_p = d;
  float a_p = 0.f;
  if (head < total) {
    s_p = (head < deg) ? csr_src[start + head] : d;
    a_p = al_s[(size_t)s_p * 8 + hh];
  }

  for (int e0 = 0; e0 < total; e0 += 8) {
    const int el = e0 + head;
    const int s_j = s_p;
    float v = a_p + ald_c;
    v = fmaxf(v, NEG_SLOPE * v);
    const float u = (el < total) ? __expf(v) : 0.f;
    den += u;
    // prefetch next group (independent of this group's fma block)
    const int eln = el + 8;
    if (eln < total) {
      s_p = (eln < deg) ? csr_src[start + eln] : d;
      a_p = al_s[(size_t)s_p * 8 + hh];
    } else {
      s_p = d;
      a_p = 0.f;
    }
#pragma unroll
    for (int e = 0; e < 8; ++e) {
      const float a = __shfl(u, e * 8 + head);
      const int s = __shfl(s_j, e * 8);
      const uint4 uu = *(const uint4*)(h1l + (size_t)s * 512);
      acc[0] = fmaf(a, lo16(uu.x), acc[0]);
      acc[1] = fmaf(a, hi16(uu.x), acc[1]);
      acc[2] = fmaf(a, lo16(uu.y), acc[2]);
      acc[3] = fmaf(a, hi16(uu.y), acc[3]);
      acc[4] = fmaf(a, lo16(uu.z), acc[4]);
      acc[5] = fmaf(a, hi16(uu.z), acc[5]);
      acc[6] = fmaf(a, lo16(uu.w), acc[6]);
      acc[7] = fmaf(a, hi16(uu.w), acc[7]);
    }
  }
  // reduce den over lanes with same (l&7): xor 8,16,32 preserves l&7
  den += __shfl_xor(den, 8);
  den += __shfl_xor(den, 16);
  den += __shfl_xor(den, 32);
  const float inv = 1.f / __shfl(den, head);

  const float4 bb0 = *(const float4*)(b1 + l * 8);
  const float4 bb1 = *(const float4*)(b1 + l * 8 + 4);
  float o[8];
  o[0] = acc[0] * inv + bb0.x;
  o[1] = acc[1] * inv + bb0.y;
  o[2] = acc[2] * inv + bb0.z;
  o[3] = acc[3] * inv + bb0.w;
  o[4] = acc[4] * inv + bb1.x;
  o[5] = acc[5] * inv + bb1.y;
  o[6] = acc[6] * inv + bb1.z;
  o[7] = acc[7] * inv + bb1.w;
#pragma unroll
  for (int k = 0; k < 8; ++k) o[k] = (o[k] > 0.f) ? o[k] : __expf(o[k]) - 1.f;
  uint4 st;
  st.x = (uint32_t)f2bf(o[0]) | ((uint32_t)f2bf(o[1]) << 16);
  st.y = (uint32_t)f2bf(o[2]) | ((uint32_t)f2bf(o[3]) << 16);
  st.z = (uint32_t)f2bf(o[4]) | ((uint32_t)f2bf(o[5]) << 16);
  st.w = (uint32_t)f2bf(o[6]) | ((uint32_t)f2bf(o[7]) << 16);
  *(uint4*)(out1 + (size_t)d * 512 + l * 8) = st;
}

// ---------------------------------------------------------------------------
// Attention layer 2: H=1, C=64, h bf16. One wave per node -> out bf16.
// ---------------------------------------------------------------------------
__global__ __launch_bounds__(256) void attn_h1_kernel(
    const int* __restrict__ indptr, const int* __restrict__ csr_src,
    const float* __restrict__ al_s, const float* __restrict__ al_d,
    const ushort* __restrict__ hin, const float* __restrict__ bias,
    ushort* __restrict__ outp, int Nn) {
  int w = (blockIdx.x * 256 + threadIdx.x) >> 6;
  int lane = threadIdx.x & 63;
  if (w >= Nn) return;
  const int d = w;
  const int start = indptr[d];
  const int deg = indptr[d + 1] - start;
  const int total = deg + 1;
  const float ald = al_d[d];

  float acc = 0.f, den = 0.f;
  for (int e0 = 0; e0 < total; e0 += 64) {
    int e = e0 + lane;
    int s_j = d;
    float u = 0.f;
    if (e < total) {
      s_j = (e < deg) ? csr_src[start + e] : d;
      float v = al_s[s_j] + ald;
      v = fmaxf(v, NEG_SLOPE * v);
      u = __expf(v);
      den += u;
    }
    int ne = min(64, total - e0);
    for (int j = 0; j < ne; j += 8) {
      float av[8];
      int sv[8];
#pragma unroll
      for (int k = 0; k < 8; ++k) {
        av[k] = __shfl(u, j + k);
        sv[k] = __shfl(s_j, j + k);
      }
      float hv[8];
#pragma unroll
      for (int k = 0; k < 8; ++k)
        hv[k] = bf2f(hin[(size_t)sv[k] * 64 + lane]);
#pragma unroll
      for (int k = 0; k < 8; ++k) acc = fmaf(av[k], hv[k], acc);
    }
  }
#pragma unroll
  for (int off = 32; off; off >>= 1) den += __shfl_xor(den, off);
  float v = acc / den + bias[lane];
  v = (v > 0.f) ? v : __expf(v) - 1.f;
  outp[(size_t)d * 64 + lane] = f2bf(v);
}

// ---------------------------------------------------------------------------
// Attention layer 3 + pooling: same attention, but instead of storing out3,
// atomically accumulate into per-graph sums (batch sorted; low contention).
// ---------------------------------------------------------------------------
__global__ __launch_bounds__(256) void attn_h1_pool_kernel(
    const int* __restrict__ indptr, const int* __restrict__ csr_src,
    const float* __restrict__ al_s, const float* __restrict__ al_d,
    const ushort* __restrict__ hin, const float* __restrict__ bias,
    const int* __restrict__ batch, float* __restrict__ sums, int Nn) {
  int w = (blockIdx.x * 256 + threadIdx.x) >> 6;
  int lane = threadIdx.x & 63;
  if (w >= Nn) return;
  const int d = w;
  const int start = indptr[d];
  const int deg = indptr[d + 1] - start;
  const int total = deg + 1;
  const float ald = al_d[d];

  float acc = 0.f, den = 0.f;
  for (int e0 = 0; e0 < total; e0 += 64) {
    int e = e0 + lane;
    int s_j = d;
    float u = 0.f;
    if (e < total) {
      s_j = (e < deg) ? csr_src[start + e] : d;
      float v = al_s[s_j] + ald;
      v = fmaxf(v, NEG_SLOPE * v);
      u = __expf(v);
      den += u;
    }
    int ne = min(64, total - e0);
    for (int j = 0; j < ne; j += 8) {
      float av[8];
      int sv[8];
#pragma unroll
      for (int k = 0; k < 8; ++k) {
        av[k] = __shfl(u, j + k);
        sv[k] = __shfl(s_j, j + k);
      }
      float hv[8];
#pragma unroll
      for (int k = 0; k < 8; ++k)
        hv[k] = bf2f(hin[(size_t)sv[k] * 64 + lane]);
#pragma unroll
      for (int k = 0; k < 8; ++k) acc = fmaf(av[k], hv[k], acc);
    }
  }
#pragma unroll
  for (int off = 32; off; off >>= 1) den += __shfl_xor(den, off);
  float v = acc / den + bias[lane];
  v = (v > 0.f) ? v : __expf(v) - 1.f;
  atomicAdd(&sums[batch[d] * 64 + lane], v);
}

// ---------------------------------------------------------------------------
// Final FC on pooled sums. One block.
// ---------------------------------------------------------------------------
__global__ __launch_bounds__(256) void fc_kernel(
    const float* __restrict__ sums, const int* __restrict__ batch, int Nn,
    const float* __restrict__ fcW, const float* __restrict__ fcb,
    float* __restrict__ out) {
  __shared__ int lb[65];
  __shared__ float inv_cnt[64];
  int tid = threadIdx.x;
  if (tid <= 64) {
    int lo = 0, hi = Nn;
    while (lo < hi) {
      int mid = (lo + hi) >> 1;
      if (batch[mid] < tid) lo = mid + 1; else hi = mid;
    }
    lb[tid] = lo;
  }
  __syncthreads();
  if (tid < 64) inv_cnt[tid] = 1.f / fmaxf((float)(lb[tid + 1] - lb[tid]), 1.f);
  __syncthreads();
  for (int i = tid; i < 64 * 10; i += 256) {
    int g = i / 10, o = i % 10;
    float acc = fcb[o];
    float inv = inv_cnt[g];
    for (int c = 0; c < 64; ++c)
      acc = fmaf(sums[g * 64 + c] * inv, fcW[c * 10 + o], acc);
    out[i] = acc;
  }
}

// ---------------------------------------------------------------------------
extern "C" void kernel_launch(void* const* d_in, const int* in_sizes, int n_in,
                              void* d_out, int out_size, void* d_ws,
                              size_t ws_size, hipStream_t stream) {
  const float* x = (const float*)d_in[0];
  const int* ei = (const int*)d_in[1];
  const int* batch = (const int*)d_in[2];
  const float* W1 = (const float*)d_in[3];
  const float* a1s = (const float*)d_in[4];
  const float* a1d = (const float*)d_in[5];
  const float* b1 = (const float*)d_in[6];
  const float* W2 = (const float*)d_in[7];
  const float* a2s = (const float*)d_in[8];
  const float* a2d = (const float*)d_in[9];
  const float* b2 = (const float*)d_in[10];
  const float* W3 = (const float*)d_in[11];
  const float* a3s = (const float*)d_in[12];
  const float* a3d = (const float*)d_in[13];
  const float* b3 = (const float*)d_in[14];
  const float* fcW = (const float*)d_in[15];
  const float* fcb = (const float*)d_in[16];
  float* out = (float*)d_out;

  const int N = in_sizes[0] / 128;  // 50000
  const int E = in_sizes[1] / 2;    // 800000
  const int* srcp = ei;
  const int* dstp = ei + E;

  // --- workspace layout ---
  char* ws = (char*)d_ws;
  size_t off = 0;
  auto alloc = [&](size_t bytes) -> void* {
    off = (off + 255) & ~(size_t)255;
    void* p = ws + off;
    off += bytes;
    return p;
  };
  ushort* x_bf = (ushort*)alloc((size_t)N * 128 * 2);
  ushort* W1T = (ushort*)alloc(512 * 128 * 2);
  ushort* W2T = (ushort*)alloc(64 * 512 * 2);
  ushort* W3T = (ushort*)alloc(64 * 64 * 2);
  ushort* h1 = (ushort*)alloc((size_t)N * 512 * 2);  // reused: h2/out2/h3
  ushort* out1 = (ushort*)alloc((size_t)N * 512 * 2);
  float* al_s1 = (float*)alloc((size_t)N * 8 * 4);
  float* al_d1 = (float*)alloc((size_t)N * 8 * 4);
  float* al_s2 = (float*)alloc((size_t)N * 4);
  float* al_d2 = (float*)alloc((size_t)N * 4);
  float* al_s3 = (float*)alloc((size_t)N * 4);
  float* al_d3 = (float*)alloc((size_t)N * 4);
  int* cnt = (int*)alloc((size_t)N * 4);
  int* fill = (int*)alloc((size_t)(N + 1) * 4);
  int* indptr = (int*)alloc((size_t)(N + 1) * 4);
  int* csr = (int*)alloc((size_t)E * 4);
  int* incbuf = (int*)alloc((size_t)N * 4);
  int* bsum = (int*)alloc(1024 * 4);
  float* sums = (float*)alloc(64 * 64 * 4);

  // aliases into the (dead-after-attn1) h1 region
  ushort* h2 = h1;
  ushort* out2 = h1 + (size_t)N * 64;
  ushort* h3 = h1 + (size_t)2 * N * 64;

  hipMemsetAsync(cnt, 0, (size_t)N * 4, stream);

  const int scan_blocks = (N + 255) / 256;  // 196 (<256 required)
  const int row_blocks = (N / 16 + 3) / 4;

  // prep: x cast + weight transposes + CSR count + sums zero
  const int n_x4 = N * 128 / 4;
  const int prep_total = n_x4 + 512 * 128 + 64 * 512 + 64 * 64 + E + 64 * 64;
  prep_kernel<<<(prep_total + 255) / 256, 256, 0, stream>>>(
      (const float4*)x, (uint2*)x_bf, n_x4, W1, W1T, W2, W2T, W3, W3T, dstp,
      cnt, sums, E);

  // GEMM1 + al1
  gemm1_al<<<dim3(4, row_blocks), 256, 0, stream>>>(x_bf, W1T, h1, a1s, a1d,
                                                    al_s1, al_d1, N);
  // CSR build
  scan_block<<<scan_blocks, 256, 0, stream>>>(cnt, incbuf, bsum, N);
  scan_final2<<<scan_blocks, 256, 0, stream>>>(incbuf, bsum, indptr, fill, N);
  scatter_kernel<<<(E + 255) / 256, 256, 0, stream>>>(srcp, dstp, fill, csr, E);
  // Layer 1 attention + bias + ELU (wave per node, pipelined)
  attn1_kernel<<<(N + 3) / 4, 256, 0, stream>>>(indptr, csr, al_s1, al_d1, h1,
                                                b1, out1, N);

  // Layer 2
  gemm_n64_al<<<dim3(1, row_blocks), 256, 0, stream>>>(out1, W2T, h2, a2s, a2d,
                                                       al_s2, al_d2, N, 512);
  attn_h1_kernel<<<(N + 3) / 4, 256, 0, stream>>>(indptr, csr, al_s2, al_d2, h2,
                                                  b2, out2, N);

  // Layer 3
  gemm_n64_al<<<dim3(1, row_blocks), 256, 0, stream>>>(out2, W3T, h3, a3s, a3d,
                                                       al_s3, al_d3, N, 64);
  attn_h1_pool_kernel<<<(N + 3) / 4, 256, 0, stream>>>(
      indptr, csr, al_s3, al_d3, h3, b3, batch, sums, N);

  // Final FC
  fc_kernel<<<1, 256, 0, stream>>>(sums, batch, N, fcW, fcb, out);
}